// Round 1
// baseline (356.577 us; speedup 1.0000x reference)
//
#include <hip/hip_runtime.h>

#define NPRED 1445
#define NSORT 2048
#define NCLS  80
#define MAXDET 300
#define OUTC  86
#define CONF_T 0.6f
#define IOU_T  0.45f
#define MAX_WH 4096.0f

// Per-image LDS workspace (~55 KB)
struct SMem {
    float bx1[NPRED], by1[NPRED], bx2[NPRED], by2[NPRED]; // offset boxes
    float area[NPRED];
    float conf[NPRED];
    unsigned long long key[NSORT];   // (desc-score-bits << 32) | index
    unsigned char jcls[NPRED];
    unsigned char keep[NPRED];       // indexed by sorted rank
    int dst[MAXDET];                 // sorted-rank of each output row
    int validCount;
    int keptCount;
};

__global__ __launch_bounds__(256)
void yolo_nms_kernel(const float* __restrict__ score, float* __restrict__ out) {
    __shared__ SMem s;
    const int b = blockIdx.x;
    const int tid = threadIdx.x;
    const float* sb = score + (size_t)b * 425 * 289;

    if (tid == 0) s.validCount = 0;
    __syncthreads();

    // ---- Phase 1: per-candidate compute ----
    for (int n = tid; n < NPRED; n += 256) {
        const int hw = n / 5;
        const int t5 = n % 5;
        const float* base = sb + (size_t)(t5 * 85) * 289 + hw; // base[c*289] = x[n][c]
        float x = base[0];
        float y = base[289];
        float w = base[2 * 289];
        float h = base[3 * 289];
        float obj = base[4 * 289];

        float best = -INFINITY; int bj = 0;
        for (int k = 0; k < NCLS; ++k) {
            float v = base[(5 + k) * 289] * obj;  // cls = logits * obj
            if (v > best) { best = v; bj = k; }   // first-occurrence argmax
        }
        float conf = best;
        bool valid = (obj > CONF_T) && (conf > CONF_T);

        float wh2 = w * 0.5f, hh2 = h * 0.5f;
        float x1 = x - wh2, y1 = y - hh2, x2 = x + wh2, y2 = y + hh2;
        float off = (float)bj * MAX_WH;           // exact (int * pow2)
        float ox1 = x1 + off, oy1 = y1 + off, ox2 = x2 + off, oy2 = y2 + off;

        s.bx1[n] = ox1; s.by1[n] = oy1; s.bx2[n] = ox2; s.by2[n] = oy2;
        s.area[n] = (ox2 - ox1) * (oy2 - oy1);
        s.conf[n] = conf;
        s.jcls[n] = (unsigned char)bj;

        float sc = valid ? conf : -1.0f;
        if (valid) atomicAdd(&s.validCount, 1);

        // sortable key: descending score, ascending index tiebreak (stable argsort)
        unsigned int u = __float_as_uint(sc);
        unsigned int asc = (u & 0x80000000u) ? ~u : (u | 0x80000000u); // ascending order
        unsigned int desc = ~asc;                                      // descending order
        s.key[n] = ((unsigned long long)desc << 32) | (unsigned int)n;
    }
    for (int n = NPRED + tid; n < NSORT; n += 256) s.key[n] = ~0ULL; // pad to end
    __syncthreads();

    // ---- Phase 2: bitonic sort (ascending 64-bit keys) ----
    for (int k = 2; k <= NSORT; k <<= 1) {
        for (int j = k >> 1; j > 0; j >>= 1) {
            for (int i = tid; i < NSORT; i += 256) {
                int l = i ^ j;
                if (l > i) {
                    unsigned long long a = s.key[i], c = s.key[l];
                    bool up = ((i & k) == 0);
                    if ((a > c) == up) { s.key[i] = c; s.key[l] = a; }
                }
            }
            __syncthreads();
        }
    }

    // ---- Phase 3: greedy NMS over sorted valid entries ----
    int M = s.validCount;                 // valid entries sort first (conf>0.6 > -1)
    for (int r = tid; r < NPRED; r += 256) s.keep[r] = (r < M) ? 1 : 0;
    __syncthreads();

    for (int i = 0; i < M; ++i) {
        if (s.keep[i]) {                  // uniform read (same value all threads)
            int ni = (unsigned int)s.key[i];
            float ax1 = s.bx1[ni], ay1 = s.by1[ni];
            float ax2 = s.bx2[ni], ay2 = s.by2[ni];
            float aa  = s.area[ni];
            for (int r = i + 1 + tid; r < M; r += 256) {
                int nj = (unsigned int)s.key[r];
                float ltx = fmaxf(ax1, s.bx1[nj]);
                float lty = fmaxf(ay1, s.by1[nj]);
                float rbx = fminf(ax2, s.bx2[nj]);
                float rby = fminf(ay2, s.by2[nj]);
                float ww = fmaxf(rbx - ltx, 0.0f);
                float hh = fmaxf(rby - lty, 0.0f);
                float inter = ww * hh;
                float denom = ((aa + s.area[nj]) - inter) + 1e-9f; // left-to-right
                float iou = inter / denom;
                if (iou > IOU_T) s.keep[r] = 0;
            }
        }
        __syncthreads();
    }

    // ---- Phase 4: serial compaction (rank order) ----
    if (tid == 0) {
        int cnt = 0;
        for (int r = 0; r < M && cnt < MAXDET; ++r)
            if (s.keep[r]) s.dst[cnt++] = r;
        s.keptCount = cnt;
    }
    __syncthreads();
    const int cnt = s.keptCount;

    // ---- Phase 5: output 300 x 86 rows (zeros beyond kept) ----
    float* ob = out + (size_t)b * MAXDET * OUTC;
    for (int e = tid; e < MAXDET * OUTC; e += 256) {
        int row = e / OUTC, c = e % OUTC;
        float v = 0.0f;
        if (row < cnt) {
            int r = s.dst[row];
            int n = (unsigned int)s.key[r];
            int hw = n / 5, t5 = n % 5;
            const float* base = sb + (size_t)(t5 * 85) * 289 + hw;
            if (c < 4) {
                float x = base[0];
                float y = base[289];
                float w = base[2 * 289];
                float h = base[3 * 289];
                float wh2 = w * 0.5f, hh2 = h * 0.5f;
                if      (c == 0) v = x - wh2;
                else if (c == 1) v = y - hh2;
                else if (c == 2) v = x + wh2;
                else             v = y + hh2;
            } else if (c == 4) {
                v = s.conf[n];
            } else if (c == 5) {
                v = (float)s.jcls[n];
            } else {
                v = base[(c - 1) * 289];  // raw logits
            }
        }
        ob[e] = v;
    }
}

extern "C" void kernel_launch(void* const* d_in, const int* in_sizes, int n_in,
                              void* d_out, int out_size, void* d_ws, size_t ws_size,
                              hipStream_t stream) {
    const float* score = (const float*)d_in[0];
    float* out = (float*)d_out;
    yolo_nms_kernel<<<32, 256, 0, stream>>>(score, out);
}

// Round 2
// 164.091 us; speedup vs baseline: 2.1730x; 2.1730x over previous
//
#include <hip/hip_runtime.h>

#define NPRED 1445
#define NCLS  80
#define MAXDET 300
#define OUTC  86
#define CONF_T 0.6f
#define IOU_T  0.45f
#define MAX_WH 4096.0f
#define HWSZ  289
#define MCAP  512   // suppression-matrix path handles M <= MCAP (mean ~390, sigma ~17)

struct SMem {
    float bx1[NPRED], by1[NPRED], bx2[NPRED], by2[NPRED], area[NPRED]; // offset boxes
    unsigned short sortedN[NPRED];          // rank -> candidate n
    union {
        unsigned long long vkey[NPRED];     // phase 1-2: (desc conf bits)<<32 | n
        unsigned long long supMat[MCAP * 8];// phase 3-4: suppression bitmask rows
        struct { float confR[MAXDET]; unsigned char jclsR[MAXDET]; } oi; // phase 5
        unsigned char keepFB[NPRED];        // fallback path keep flags
    } u;
    unsigned short dstN[MAXDET];            // output row -> candidate n
    int validCount;
    int keptCount;
};

__device__ __forceinline__ void conf_argmax(const float* __restrict__ base, float obj,
                                            float& conf, int& bj) {
    float best = -INFINITY; int bjj = 0;
    #pragma unroll 8
    for (int k = 0; k < NCLS; ++k) {
        float v = base[(5 + k) * HWSZ] * obj;   // cls = logits * obj
        if (v > best) { best = v; bjj = k; }    // strict > : first-occurrence argmax
    }
    conf = best; bj = bjj;
}

__global__ __launch_bounds__(1024)
void yolo_nms_kernel(const float* __restrict__ score, float* __restrict__ out) {
    __shared__ SMem s;
    const int b = blockIdx.x;
    const int tid = threadIdx.x;
    const float* sb = score + (size_t)b * 425 * HWSZ;

    if (tid == 0) s.validCount = 0;
    __syncthreads();

    // ---- Phase 1: per-candidate compute (coalesced: lanes span consecutive hw) ----
    for (int ci = tid; ci < NPRED; ci += 1024) {
        int t5 = ci / HWSZ;
        int hw = ci - t5 * HWSZ;
        int n = hw * 5 + t5;                       // candidate row index in x[N][85]
        const float* base = sb + (size_t)(t5 * 85) * HWSZ + hw;
        float x = base[0];
        float y = base[HWSZ];
        float w = base[2 * HWSZ];
        float h = base[3 * HWSZ];
        float obj = base[4 * HWSZ];
        float conf; int bj;
        conf_argmax(base, obj, conf, bj);
        bool valid = (obj > CONF_T) && (conf > CONF_T);

        float wh2 = w * 0.5f, hh2 = h * 0.5f;
        float x1 = x - wh2, y1 = y - hh2, x2 = x + wh2, y2 = y + hh2;
        float off = (float)bj * MAX_WH;            // exact product
        float ox1 = x1 + off, oy1 = y1 + off, ox2 = x2 + off, oy2 = y2 + off;
        s.bx1[n] = ox1; s.by1[n] = oy1; s.bx2[n] = ox2; s.by2[n] = oy2;
        s.area[n] = (ox2 - ox1) * (oy2 - oy1);

        if (valid) {
            int slot = atomicAdd(&s.validCount, 1);
            unsigned int uu = __float_as_uint(conf);         // conf > 0.6 -> positive float
            unsigned int desc = ~(uu | 0x80000000u);         // descending-order bits
            s.u.vkey[slot] = ((unsigned long long)desc << 32) | (unsigned int)n;
        }
    }
    __syncthreads();
    const int M = s.validCount;

    // ---- Phase 2: rank-by-counting sort (keys unique; broadcast LDS reads) ----
    for (int vi = tid; vi < M; vi += 1024) {
        unsigned long long ki = s.u.vkey[vi];
        int rank = 0;
        #pragma unroll 4
        for (int j = 0; j < M; ++j) rank += (s.u.vkey[j] < ki) ? 1 : 0;
        s.sortedN[rank] = (unsigned short)(ki & 0xFFFFULL);
    }
    __syncthreads();

    if (M <= MCAP) {
        // ---- Phase 3: suppression bitmask matrix, one ballot word per wave-task ----
        const int NW = (M + 63) >> 6;
        const int wid = tid >> 6, lane = tid & 63;
        for (int t = wid; t < M * NW; t += 16) {
            int i = t / NW, w = t - i * NW;
            int ni = s.sortedN[i];
            float ax1 = s.bx1[ni], ay1 = s.by1[ni];
            float ax2 = s.bx2[ni], ay2 = s.by2[ni];
            float aa  = s.area[ni];
            int j = (w << 6) + lane;
            bool sup = false;
            if (j < M && j > i) {
                int nj = s.sortedN[j];
                float ltx = fmaxf(ax1, s.bx1[nj]);
                float lty = fmaxf(ay1, s.by1[nj]);
                float rbx = fminf(ax2, s.bx2[nj]);
                float rby = fminf(ay2, s.by2[nj]);
                float ww = fmaxf(rbx - ltx, 0.0f);
                float hh = fmaxf(rby - lty, 0.0f);
                float inter = ww * hh;
                float denom = ((aa + s.area[nj]) - inter) + 1e-9f;
                sup = (inter / denom) > IOU_T;
            }
            unsigned long long mask = __ballot(sup);
            if (lane == 0) s.u.supMat[t] = mask;
        }
        __syncthreads();

        // ---- Phase 4: single-wave greedy scan (no barriers, dist-2 prefetch) ----
        if (tid < 64) {
            const int lane = tid;
            unsigned long long keepW = 0;
            int rem = M - (lane << 6);
            if (rem >= 64) keepW = ~0ULL;
            else if (rem > 0) keepW = (~0ULL) >> (64 - rem);
            unsigned long long supA = (lane < NW && M > 0) ? s.u.supMat[lane] : 0ULL;
            unsigned long long supB = (lane < NW && M > 1) ? s.u.supMat[NW + lane] : 0ULL;
            int cnt = 0;
            for (int i = 0; i < M; ++i) {
                unsigned long long supNext =
                    (lane < NW && (i + 2) < M) ? s.u.supMat[(i + 2) * NW + lane] : 0ULL;
                unsigned long long wv = __shfl(keepW, i >> 6, 64);
                if ((wv >> (i & 63)) & 1ULL) {
                    keepW &= ~supA;
                    if (lane == 0 && cnt < MAXDET) s.dstN[cnt] = s.sortedN[i];
                    cnt++;
                }
                supA = supB; supB = supNext;
            }
            if (lane == 0) s.keptCount = (cnt < MAXDET) ? cnt : MAXDET;
        }
        __syncthreads();
    } else {
        // ---- Fallback (M > MCAP, not expected): serial greedy NMS ----
        for (int r = tid; r < M; r += 1024) s.u.keepFB[r] = 1;
        __syncthreads();
        for (int i = 0; i < M; ++i) {
            if (s.u.keepFB[i]) {
                int ni = s.sortedN[i];
                float ax1 = s.bx1[ni], ay1 = s.by1[ni];
                float ax2 = s.bx2[ni], ay2 = s.by2[ni];
                float aa  = s.area[ni];
                for (int r = i + 1 + tid; r < M; r += 1024) {
                    int nj = s.sortedN[r];
                    float ltx = fmaxf(ax1, s.bx1[nj]);
                    float lty = fmaxf(ay1, s.by1[nj]);
                    float rbx = fminf(ax2, s.bx2[nj]);
                    float rby = fminf(ay2, s.by2[nj]);
                    float ww = fmaxf(rbx - ltx, 0.0f);
                    float hh = fmaxf(rby - lty, 0.0f);
                    float inter = ww * hh;
                    float denom = ((aa + s.area[nj]) - inter) + 1e-9f;
                    if ((inter / denom) > IOU_T) s.u.keepFB[r] = 0;
                }
            }
            __syncthreads();
        }
        if (tid == 0) {
            int cnt = 0;
            for (int r = 0; r < M && cnt < MAXDET; ++r)
                if (s.u.keepFB[r]) s.dstN[cnt++] = s.sortedN[r];
            s.keptCount = cnt;
        }
        __syncthreads();
    }

    // ---- Phase 5a: conf/class for kept rows only (<=300, L2-hot re-reads) ----
    const int cnt = s.keptCount;
    if (tid < cnt) {
        int n = s.dstN[tid];
        int hw = n / 5, t5 = n - hw * 5;
        const float* base = sb + (size_t)(t5 * 85) * HWSZ + hw;
        float obj = base[4 * HWSZ];
        float conf; int bj;
        conf_argmax(base, obj, conf, bj);
        s.u.oi.confR[tid] = conf;
        s.u.oi.jclsR[tid] = (unsigned char)bj;
    }
    __syncthreads();

    // ---- Phase 5b: write 300 x 86 output rows (zeros beyond kept) ----
    float* ob = out + (size_t)b * MAXDET * OUTC;
    for (int e = tid; e < MAXDET * OUTC; e += 1024) {
        int row = e / OUTC, c = e - row * OUTC;
        float v = 0.0f;
        if (row < cnt) {
            int n = s.dstN[row];
            int hw = n / 5, t5 = n - hw * 5;
            const float* base = sb + (size_t)(t5 * 85) * HWSZ + hw;
            if (c < 4) {
                float x = base[0];
                float y = base[HWSZ];
                float w = base[2 * HWSZ];
                float h = base[3 * HWSZ];
                float wh2 = w * 0.5f, hh2 = h * 0.5f;
                v = (c == 0) ? (x - wh2) : (c == 1) ? (y - hh2)
                  : (c == 2) ? (x + wh2) : (y + hh2);
            } else if (c == 4) {
                v = s.u.oi.confR[row];
            } else if (c == 5) {
                v = (float)s.u.oi.jclsR[row];
            } else {
                v = base[(c - 1) * HWSZ];   // raw logits
            }
        }
        ob[e] = v;
    }
}

extern "C" void kernel_launch(void* const* d_in, const int* in_sizes, int n_in,
                              void* d_out, int out_size, void* d_ws, size_t ws_size,
                              hipStream_t stream) {
    const float* score = (const float*)d_in[0];
    float* out = (float*)d_out;
    yolo_nms_kernel<<<32, 1024, 0, stream>>>(score, out);
}

// Round 3
// 156.376 us; speedup vs baseline: 2.2803x; 1.0493x over previous
//
#include <hip/hip_runtime.h>

#define NPRED 1445
#define NCLS  80
#define MAXDET 300
#define OUTC  86
#define CONF_T 0.6f
#define IOU_T  0.45f
#define MAX_WH 4096.0f
#define HWSZ  289
#define NIMG  32
#define SLOTS 768      // ws slots per image (mean M~396, sigma~17 -> 22-sigma margin)
#define MCAP  576      // bitmask-matrix path cap (10-sigma margin)
#define NWMAX 9        // ceil(576/64)

// ---- d_ws layout (bytes) ----
// [0)      wsCnt  int[32]
// [128)    wsKept int[32]
// [256)    wsKey  u64[32][SLOTS]      (desc-conf<<32 | n<<16 | cls<<8)
// [196864) wsBox  float4[32][SLOTS]   (offset x1,y1,x2,y2)
// [590080) wsDst  u16[32][MAXDET]     (slot per kept output row)
// total 609280
#define WS_NEED 609280
#define OFF_KEPT 128
#define OFF_KEY  256
#define OFF_BOX  196864
#define OFF_DST  590080

// ================= kernel 1: per-candidate prep =================
__global__ __launch_bounds__(128)
void prep_kernel(const float* __restrict__ score, int* __restrict__ wsCnt,
                 unsigned long long* __restrict__ wsKey, float4* __restrict__ wsBox) {
    const int b = blockIdx.x;
    const int ci = blockIdx.y * 128 + threadIdx.x;
    if (ci >= NPRED) return;
    const int t5 = ci / HWSZ;
    const int hw = ci - t5 * HWSZ;
    const int n = hw * 5 + t5;                     // candidate row in x[N][85]
    const float* base = score + (size_t)b * 425 * HWSZ + (size_t)(t5 * 85) * HWSZ + hw;
    float x = base[0];
    float y = base[HWSZ];
    float w = base[2 * HWSZ];
    float h = base[3 * HWSZ];
    float obj = base[4 * HWSZ];

    float best = -INFINITY; int bj = 0;
    #pragma unroll 16
    for (int k = 0; k < NCLS; ++k) {
        float v = base[(5 + k) * HWSZ] * obj;      // cls = logits * obj
        if (v > best) { best = v; bj = k; }        // strict >: first-occurrence argmax
    }
    if (!((obj > CONF_T) && (best > CONF_T))) return;

    float wh2 = w * 0.5f, hh2 = h * 0.5f;
    float x1 = x - wh2, y1 = y - hh2, x2 = x + wh2, y2 = y + hh2;
    float off = (float)bj * MAX_WH;                // exact product
    int slot = atomicAdd(&wsCnt[b], 1);
    if (slot >= SLOTS) return;                     // ~22-sigma improbable
    unsigned int u = __float_as_uint(best);        // conf > 0.6 -> positive
    unsigned int desc = ~(u | 0x80000000u);        // ascending u64 == descending conf
    wsKey[b * SLOTS + slot] = ((unsigned long long)desc << 32)
                            | ((unsigned long long)(unsigned)n << 16)
                            | ((unsigned long long)(unsigned)bj << 8);
    wsBox[b * SLOTS + slot] = make_float4(x1 + off, y1 + off, x2 + off, y2 + off);
}

// ================= kernel 2: sort + NMS =================
struct SM2 {
    union {
        unsigned long long keys[SLOTS];            // during sort
        unsigned long long supMat[MCAP * NWMAX];   // after sort (matrix path)
    } u;
    float sbx1[SLOTS], sby1[SLOTS], sbx2[SLOTS], sby2[SLOTS]; // rank-sorted boxes
    unsigned short sortedSlot[SLOTS];
    unsigned char keepFB[SLOTS];                   // fallback path only
};

__global__ __launch_bounds__(1024)
void nms_kernel(const int* __restrict__ wsCnt, const unsigned long long* __restrict__ wsKey,
                const float4* __restrict__ wsBox, int* __restrict__ wsKept,
                unsigned short* __restrict__ wsDst) {
    __shared__ SM2 s;
    const int b = blockIdx.x;
    const int tid = threadIdx.x;
    int M = wsCnt[b]; if (M > SLOTS) M = SLOTS;

    for (int i = tid; i < M; i += 1024) s.u.keys[i] = wsKey[b * SLOTS + i];
    __syncthreads();

    // rank-by-counting sort (keys unique; broadcast LDS reads)
    for (int vi = tid; vi < M; vi += 1024) {
        unsigned long long ki = s.u.keys[vi];
        int rank = 0;
        #pragma unroll 4
        for (int j = 0; j < M; ++j) rank += (s.u.keys[j] < ki) ? 1 : 0;
        s.sortedSlot[rank] = (unsigned short)vi;
    }
    __syncthreads();

    // rank-sorted box arrays (all later reads consecutive-address -> conflict-free)
    for (int r = tid; r < M; r += 1024) {
        float4 bx = wsBox[b * SLOTS + s.sortedSlot[r]];
        s.sbx1[r] = bx.x; s.sby1[r] = bx.y; s.sbx2[r] = bx.z; s.sby2[r] = bx.w;
    }
    __syncthreads();

    if (M <= MCAP) {
        // ---- suppression bitmask matrix: one ballot word per wave-task ----
        const int NW = (M + 63) >> 6;
        const int wid = tid >> 6, lane = tid & 63;
        for (int t = wid; t < M * NW; t += 16) {
            int i = t / NW, w = t - i * NW;
            float ax1 = s.sbx1[i], ay1 = s.sby1[i];
            float ax2 = s.sbx2[i], ay2 = s.sby2[i];
            float aa  = (ax2 - ax1) * (ay2 - ay1);
            int j = (w << 6) + lane;
            bool sup = false;
            if (j < M && j > i) {
                float bx1 = s.sbx1[j], by1 = s.sby1[j];
                float bx2 = s.sbx2[j], by2 = s.sby2[j];
                float ab  = (bx2 - bx1) * (by2 - by1);
                float ltx = fmaxf(ax1, bx1);
                float lty = fmaxf(ay1, by1);
                float rbx = fminf(ax2, bx2);
                float rby = fminf(ay2, by2);
                float ww = fmaxf(rbx - ltx, 0.0f);
                float hh = fmaxf(rby - lty, 0.0f);
                float inter = ww * hh;
                float denom = ((aa + ab) - inter) + 1e-9f;   // left-to-right
                sup = (inter / denom) > IOU_T;
            }
            unsigned long long mask = __ballot(sup);
            if (lane == 0) s.u.supMat[t] = mask;
        }
        __syncthreads();

        // ---- single-wave greedy bit-scan (no barriers, dist-2 prefetch) ----
        if (tid < 64) {
            const int lane = tid;
            const int NW2 = NW;
            unsigned long long keepW = 0;
            int rem = M - (lane << 6);
            if (rem >= 64) keepW = ~0ULL;
            else if (rem > 0) keepW = (~0ULL) >> (64 - rem);
            unsigned long long supA = (lane < NW2 && M > 0) ? s.u.supMat[lane] : 0ULL;
            unsigned long long supB = (lane < NW2 && M > 1) ? s.u.supMat[NW2 + lane] : 0ULL;
            int cnt = 0;
            for (int i = 0; i < M; ++i) {
                unsigned long long supN =
                    (lane < NW2 && (i + 2) < M) ? s.u.supMat[(i + 2) * NW2 + lane] : 0ULL;
                unsigned long long wv = __shfl(keepW, i >> 6, 64);
                if ((wv >> (i & 63)) & 1ULL) {
                    keepW &= ~supA;
                    if (lane == 0 && cnt < MAXDET) wsDst[b * MAXDET + cnt] = s.sortedSlot[i];
                    cnt++;
                }
                supA = supB; supB = supN;
            }
            if (lane == 0) wsKept[b] = (cnt < MAXDET) ? cnt : MAXDET;
        }
    } else {
        // ---- fallback (M > MCAP, ~0 probability): barrier-serial greedy ----
        for (int r = tid; r < M; r += 1024) s.keepFB[r] = 1;
        __syncthreads();
        for (int i = 0; i < M; ++i) {
            if (s.keepFB[i]) {
                float ax1 = s.sbx1[i], ay1 = s.sby1[i];
                float ax2 = s.sbx2[i], ay2 = s.sby2[i];
                float aa  = (ax2 - ax1) * (ay2 - ay1);
                for (int r = i + 1 + tid; r < M; r += 1024) {
                    float bx1 = s.sbx1[r], by1 = s.sby1[r];
                    float bx2 = s.sbx2[r], by2 = s.sby2[r];
                    float ab  = (bx2 - bx1) * (by2 - by1);
                    float ltx = fmaxf(ax1, bx1);
                    float lty = fmaxf(ay1, by1);
                    float rbx = fminf(ax2, bx2);
                    float rby = fminf(ay2, by2);
                    float ww = fmaxf(rbx - ltx, 0.0f);
                    float hh = fmaxf(rby - lty, 0.0f);
                    float inter = ww * hh;
                    float denom = ((aa + ab) - inter) + 1e-9f;
                    if ((inter / denom) > IOU_T) s.keepFB[r] = 0;
                }
            }
            __syncthreads();
        }
        if (tid == 0) {
            int cnt = 0;
            for (int r = 0; r < M && cnt < MAXDET; ++r)
                if (s.keepFB[r]) wsDst[b * MAXDET + cnt++] = s.sortedSlot[r];
            wsKept[b] = cnt;
        }
    }
}

// ================= kernel 3: output write =================
__global__ __launch_bounds__(256)
void out_kernel(const float* __restrict__ score, const int* __restrict__ wsKept,
                const unsigned long long* __restrict__ wsKey,
                const unsigned short* __restrict__ wsDst, float* __restrict__ out) {
    const int b = blockIdx.x;
    const int e = blockIdx.y * 256 + threadIdx.x;
    if (e >= MAXDET * OUTC) return;
    const int row = e / OUTC, c = e - row * OUTC;
    float v = 0.0f;
    if (row < wsKept[b]) {
        unsigned long long key = wsKey[b * SLOTS + wsDst[b * MAXDET + row]];
        int n = (int)((key >> 16) & 0xFFFFULL);
        int cls = (int)((key >> 8) & 0xFFULL);
        int hw = n / 5, t5 = n - hw * 5;
        const float* base = score + (size_t)b * 425 * HWSZ + (size_t)(t5 * 85) * HWSZ + hw;
        if (c < 4) {
            float x = base[0];
            float y = base[HWSZ];
            float w = base[2 * HWSZ];
            float h = base[3 * HWSZ];
            float wh2 = w * 0.5f, hh2 = h * 0.5f;
            v = (c == 0) ? (x - wh2) : (c == 1) ? (y - hh2)
              : (c == 2) ? (x + wh2) : (y + hh2);
        } else if (c == 4) {
            v = __uint_as_float((~(unsigned int)(key >> 32)) & 0x7FFFFFFFu);
        } else if (c == 5) {
            v = (float)cls;
        } else {
            v = base[(c - 1) * HWSZ];              // raw logits
        }
    }
    out[(size_t)b * MAXDET * OUTC + e] = v;
}

// ================= fallback: proven round-2 single kernel =================
struct SMemFB {
    float bx1[NPRED], by1[NPRED], bx2[NPRED], by2[NPRED], area[NPRED];
    unsigned short sortedN[NPRED];
    union {
        unsigned long long vkey[NPRED];
        unsigned long long supMat[512 * 8];
        struct { float confR[MAXDET]; unsigned char jclsR[MAXDET]; } oi;
        unsigned char keepFB[NPRED];
    } u;
    unsigned short dstN[MAXDET];
    int validCount;
    int keptCount;
};

__device__ __forceinline__ void conf_argmax(const float* __restrict__ base, float obj,
                                            float& conf, int& bj) {
    float best = -INFINITY; int bjj = 0;
    #pragma unroll 8
    for (int k = 0; k < NCLS; ++k) {
        float v = base[(5 + k) * HWSZ] * obj;
        if (v > best) { best = v; bjj = k; }
    }
    conf = best; bj = bjj;
}

__global__ __launch_bounds__(1024)
void yolo_nms_single(const float* __restrict__ score, float* __restrict__ out) {
    __shared__ SMemFB s;
    const int b = blockIdx.x;
    const int tid = threadIdx.x;
    const float* sb = score + (size_t)b * 425 * HWSZ;
    if (tid == 0) s.validCount = 0;
    __syncthreads();
    for (int ci = tid; ci < NPRED; ci += 1024) {
        int t5 = ci / HWSZ;
        int hw = ci - t5 * HWSZ;
        int n = hw * 5 + t5;
        const float* base = sb + (size_t)(t5 * 85) * HWSZ + hw;
        float x = base[0], y = base[HWSZ], w = base[2 * HWSZ], h = base[3 * HWSZ];
        float obj = base[4 * HWSZ];
        float conf; int bj;
        conf_argmax(base, obj, conf, bj);
        bool valid = (obj > CONF_T) && (conf > CONF_T);
        float wh2 = w * 0.5f, hh2 = h * 0.5f;
        float x1 = x - wh2, y1 = y - hh2, x2 = x + wh2, y2 = y + hh2;
        float off = (float)bj * MAX_WH;
        float ox1 = x1 + off, oy1 = y1 + off, ox2 = x2 + off, oy2 = y2 + off;
        s.bx1[n] = ox1; s.by1[n] = oy1; s.bx2[n] = ox2; s.by2[n] = oy2;
        s.area[n] = (ox2 - ox1) * (oy2 - oy1);
        if (valid) {
            int slot = atomicAdd(&s.validCount, 1);
            unsigned int uu = __float_as_uint(conf);
            unsigned int desc = ~(uu | 0x80000000u);
            s.u.vkey[slot] = ((unsigned long long)desc << 32) | (unsigned int)n;
        }
    }
    __syncthreads();
    const int M = s.validCount;
    for (int vi = tid; vi < M; vi += 1024) {
        unsigned long long ki = s.u.vkey[vi];
        int rank = 0;
        for (int j = 0; j < M; ++j) rank += (s.u.vkey[j] < ki) ? 1 : 0;
        s.sortedN[rank] = (unsigned short)(ki & 0xFFFFULL);
    }
    __syncthreads();
    {
        for (int r = tid; r < M; r += 1024) s.u.keepFB[r] = 1;
        __syncthreads();
        for (int i = 0; i < M; ++i) {
            if (s.u.keepFB[i]) {
                int ni = s.sortedN[i];
                float ax1 = s.bx1[ni], ay1 = s.by1[ni], ax2 = s.bx2[ni], ay2 = s.by2[ni];
                float aa = s.area[ni];
                for (int r = i + 1 + tid; r < M; r += 1024) {
                    int nj = s.sortedN[r];
                    float ltx = fmaxf(ax1, s.bx1[nj]);
                    float lty = fmaxf(ay1, s.by1[nj]);
                    float rbx = fminf(ax2, s.bx2[nj]);
                    float rby = fminf(ay2, s.by2[nj]);
                    float ww = fmaxf(rbx - ltx, 0.0f);
                    float hh = fmaxf(rby - lty, 0.0f);
                    float inter = ww * hh;
                    float denom = ((aa + s.area[nj]) - inter) + 1e-9f;
                    if ((inter / denom) > IOU_T) s.u.keepFB[r] = 0;
                }
            }
            __syncthreads();
        }
        if (tid == 0) {
            int cnt = 0;
            for (int r = 0; r < M && cnt < MAXDET; ++r)
                if (s.u.keepFB[r]) s.dstN[cnt++] = s.sortedN[r];
            s.keptCount = cnt;
        }
        __syncthreads();
    }
    const int cnt = s.keptCount;
    if (tid < cnt) {
        int n = s.dstN[tid];
        int hw = n / 5, t5 = n - hw * 5;
        const float* base = sb + (size_t)(t5 * 85) * HWSZ + hw;
        float obj = base[4 * HWSZ];
        float conf; int bj;
        conf_argmax(base, obj, conf, bj);
        s.u.oi.confR[tid] = conf;
        s.u.oi.jclsR[tid] = (unsigned char)bj;
    }
    __syncthreads();
    float* ob = out + (size_t)b * MAXDET * OUTC;
    for (int e = tid; e < MAXDET * OUTC; e += 1024) {
        int row = e / OUTC, c = e - row * OUTC;
        float v = 0.0f;
        if (row < cnt) {
            int n = s.dstN[row];
            int hw = n / 5, t5 = n - hw * 5;
            const float* base = sb + (size_t)(t5 * 85) * HWSZ + hw;
            if (c < 4) {
                float x = base[0], y = base[HWSZ], w = base[2 * HWSZ], h = base[3 * HWSZ];
                float wh2 = w * 0.5f, hh2 = h * 0.5f;
                v = (c == 0) ? (x - wh2) : (c == 1) ? (y - hh2)
                  : (c == 2) ? (x + wh2) : (y + hh2);
            } else if (c == 4) {
                v = s.u.oi.confR[row];
            } else if (c == 5) {
                v = (float)s.u.oi.jclsR[row];
            } else {
                v = base[(c - 1) * HWSZ];
            }
        }
        ob[e] = v;
    }
}

extern "C" void kernel_launch(void* const* d_in, const int* in_sizes, int n_in,
                              void* d_out, int out_size, void* d_ws, size_t ws_size,
                              hipStream_t stream) {
    const float* score = (const float*)d_in[0];
    float* out = (float*)d_out;
    if (ws_size < (size_t)WS_NEED) {
        yolo_nms_single<<<NIMG, 1024, 0, stream>>>(score, out);
        return;
    }
    char* ws = (char*)d_ws;
    int* wsCnt = (int*)ws;
    int* wsKept = (int*)(ws + OFF_KEPT);
    unsigned long long* wsKey = (unsigned long long*)(ws + OFF_KEY);
    float4* wsBox = (float4*)(ws + OFF_BOX);
    unsigned short* wsDst = (unsigned short*)(ws + OFF_DST);

    hipMemsetAsync(ws, 0, 256, stream);  // zero wsCnt + wsKept every call
    prep_kernel<<<dim3(NIMG, 12), 128, 0, stream>>>(score, wsCnt, wsKey, wsBox);
    nms_kernel<<<NIMG, 1024, 0, stream>>>(wsCnt, wsKey, wsBox, wsKept, wsDst);
    out_kernel<<<dim3(NIMG, 101), 256, 0, stream>>>(score, wsKept, wsKey, wsDst, out);
}

// Round 4
// 108.594 us; speedup vs baseline: 3.2836x; 1.4400x over previous
//
#include <hip/hip_runtime.h>

#define NPRED 1445
#define NCLS  80
#define MAXDET 300
#define OUTC  86
#define CONF_T 0.6f
#define IOU_T  0.45f
#define MAX_WH 4096.0f
#define HWSZ  289
#define NIMG  32
#define SLOTS 768      // ws slots per image (M mean ~396, sigma ~17)
#define MCAP  512      // fast-path cap (~7 sigma)
#define NWP   8        // MCAP/64 words per suppression row

// ---- d_ws layout (bytes) ----
#define OFF_KEPT 128        // int[32]
#define OFF_KEY  256        // u64[32][SLOTS]
#define OFF_BOX  196864     // float4[32][SLOTS]   (unsorted, by slot)
#define OFF_DST  590080     // int[32][MAXDET]     (slot per kept output row)
#define OFF_SLOT 628480     // int[32][SLOTS]      (rank -> slot)
#define OFF_SBOX 726784     // float4[32][SLOTS]   (rank-sorted boxes)
#define OFF_SUP  1120000    // u64[32][MCAP][NWP]  (suppression bitmask rows)
#define WS_FULL  2168576
#define WS_MID   628480

__device__ __forceinline__ unsigned long long bcast64(unsigned long long v, int srcLane) {
    unsigned lo = (unsigned)__builtin_amdgcn_readlane((int)(unsigned)(v & 0xFFFFFFFFULL), srcLane);
    unsigned hi = (unsigned)__builtin_amdgcn_readlane((int)(unsigned)(v >> 32), srcLane);
    return ((unsigned long long)hi << 32) | lo;
}

// ================= kernel 1: per-candidate prep =================
__global__ __launch_bounds__(128)
void prep_kernel(const float* __restrict__ score, int* __restrict__ wsCnt,
                 unsigned long long* __restrict__ wsKey, float4* __restrict__ wsBox) {
    const int b = blockIdx.x;
    const int ci = blockIdx.y * 128 + threadIdx.x;
    if (ci >= NPRED) return;
    const int t5 = ci / HWSZ;
    const int hw = ci - t5 * HWSZ;
    const int n = hw * 5 + t5;                     // candidate row in x[N][85]
    const float* base = score + (size_t)b * 425 * HWSZ + (size_t)(t5 * 85) * HWSZ + hw;
    float x = base[0];
    float y = base[HWSZ];
    float w = base[2 * HWSZ];
    float h = base[3 * HWSZ];
    float obj = base[4 * HWSZ];

    float best = -INFINITY; int bj = 0;
    #pragma unroll 16
    for (int k = 0; k < NCLS; ++k) {
        float v = base[(5 + k) * HWSZ] * obj;      // cls = logits * obj
        if (v > best) { best = v; bj = k; }        // strict >: first-occurrence argmax
    }
    if (!((obj > CONF_T) && (best > CONF_T))) return;

    float wh2 = w * 0.5f, hh2 = h * 0.5f;
    float x1 = x - wh2, y1 = y - hh2, x2 = x + wh2, y2 = y + hh2;
    float off = (float)bj * MAX_WH;                // exact product
    int slot = atomicAdd(&wsCnt[b], 1);
    if (slot >= SLOTS) return;
    unsigned int u = __float_as_uint(best);        // conf > 0.6 -> positive
    unsigned int desc = ~(u | 0x80000000u);        // ascending u64 == descending conf
    wsKey[b * SLOTS + slot] = ((unsigned long long)desc << 32)
                            | ((unsigned long long)(unsigned)n << 16)
                            | ((unsigned long long)(unsigned)bj << 8);
    wsBox[b * SLOTS + slot] = make_float4(x1 + off, y1 + off, x2 + off, y2 + off);
}

// ================= kernel 2: rank-count sort =================
__global__ __launch_bounds__(1024)
void sort_kernel(const int* __restrict__ wsCnt, const unsigned long long* __restrict__ wsKey,
                 const float4* __restrict__ wsBox, int* __restrict__ wsSlot,
                 float4* __restrict__ wsSBox) {
    __shared__ unsigned long long keys[SLOTS];
    const int b = blockIdx.x, tid = threadIdx.x;
    int M = wsCnt[b]; if (M > SLOTS) M = SLOTS;
    for (int i = tid; i < M; i += 1024) keys[i] = wsKey[b * SLOTS + i];
    __syncthreads();
    if (tid < M) {                                 // M <= 768 < 1024: one key/thread
        unsigned long long ki = keys[tid];
        int rank = 0;
        #pragma unroll 4
        for (int j = 0; j < M; ++j) rank += (keys[j] < ki) ? 1 : 0;   // unique keys
        wsSlot[b * SLOTS + rank] = tid;
        wsSBox[b * SLOTS + rank] = wsBox[b * SLOTS + tid];
    }
}

// ================= kernel 3: suppression bitmask matrix =================
// grid (NIMG, NWP); block (b,w) computes word w of every row i (256 CUs busy)
__global__ __launch_bounds__(512)
void supmat_kernel(const int* __restrict__ wsCnt, const float4* __restrict__ wsSBox,
                   unsigned long long* __restrict__ supMat) {
    const int b = blockIdx.x, w = blockIdx.y, tid = threadIdx.x;
    int M = wsCnt[b]; if (M > SLOTS) M = SLOTS;
    if (M > MCAP) return;                          // fallback path handles
    __shared__ float4 box[MCAP];
    for (int r = tid; r < M; r += 512) box[r] = wsSBox[b * SLOTS + r];
    __syncthreads();
    const int lane = tid & 63, wid = tid >> 6;
    const int j = (w << 6) + lane;
    float4 jb = make_float4(0.f, 0.f, 0.f, 0.f); float ab = 0.f;
    const bool jok = (j < M);
    if (jok) { jb = box[j]; ab = (jb.z - jb.x) * (jb.w - jb.y); }
    unsigned long long* rowBase = supMat + ((size_t)b * MCAP) * NWP + w;
    if (wid >= M) return;
    float4 nxt = box[wid];
    for (int i = wid; i < M; i += 8) {
        float4 cur = nxt;
        int nx = i + 8; if (nx < M) nxt = box[nx];   // depth-1 prefetch
        float aa = (cur.z - cur.x) * (cur.w - cur.y);
        bool sup = false;
        if (jok && j > i) {
            float ltx = fmaxf(cur.x, jb.x), lty = fmaxf(cur.y, jb.y);
            float rbx = fminf(cur.z, jb.z), rby = fminf(cur.w, jb.w);
            float ww = fmaxf(rbx - ltx, 0.0f), hh = fmaxf(rby - lty, 0.0f);
            float inter = ww * hh;
            float denom = ((aa + ab) - inter) + 1e-9f;   // left-to-right, exact div
            sup = (inter / denom) > IOU_T;
        }
        unsigned long long mask = __ballot(sup);
        if (lane == 0) rowBase[(size_t)i * NWP] = mask;  // every (i<M, w) written
    }
}

// ================= kernel 4: greedy scan (1 wave, readlane + batched prefetch) =================
__global__ __launch_bounds__(256)
void scan_kernel(const int* __restrict__ wsCnt, const unsigned long long* __restrict__ supMat,
                 const int* __restrict__ wsSlot, const float4* __restrict__ wsSBox,
                 int* __restrict__ wsKept, int* __restrict__ wsDst) {
    __shared__ struct {
        float x1[SLOTS], y1[SLOTS], x2[SLOTS], y2[SLOTS];
        unsigned char kp[SLOTS];
    } fb;
    const int b = blockIdx.x, tid = threadIdx.x;
    int M = wsCnt[b]; if (M > SLOTS) M = SLOTS;

    if (M <= MCAP) {
        if (tid >= 64) return;                      // single wave; no barriers here
        const int lane = tid;
        unsigned long long keepW = 0ULL;
        int rem = M - (lane << 6);
        if (rem >= 64) keepW = ~0ULL; else if (rem > 0) keepW = (~0ULL) >> (64 - rem);
        const unsigned long long* rows = supMat + ((size_t)b * MCAP) * NWP;
        const bool ld = (lane < NWP);
        unsigned long long A[8], Bq[8];
        int cnt = 0; bool done = false;
#define LOADB(buf, bs) { _Pragma("unroll") for (int k = 0; k < 8; ++k) { \
        int ii = (bs) + k; buf[k] = (ld && ii < M) ? rows[(size_t)ii * NWP + lane] : 0ULL; } }
#define PROCB(buf, bs) { _Pragma("unroll") for (int k = 0; k < 8; ++k) { \
        int ii = (bs) + k; \
        if (!done && ii < M) { \
            unsigned long long w64 = bcast64(keepW, ii >> 6); \
            if ((w64 >> (ii & 63)) & 1ULL) { \
                keepW &= ~buf[k]; \
                if (lane == 0) wsDst[b * MAXDET + cnt] = wsSlot[b * SLOTS + ii]; \
                ++cnt; \
                if (cnt == MAXDET) done = true;   /* later bits can't reach rank<300 */ \
            } } } }
        LOADB(A, 0)
        for (int base = 0; base < M && !done; base += 16) {
            LOADB(Bq, base + 8)
            PROCB(A, base)
            LOADB(A, base + 16)
            PROCB(Bq, base + 8)
        }
#undef LOADB
#undef PROCB
        if (lane == 0) wsKept[b] = cnt;
    } else {
        // ---- fallback (M > MCAP, ~0 probability): barrier-serial greedy ----
        for (int r = tid; r < M; r += 256) {
            float4 v = wsSBox[b * SLOTS + r];
            fb.x1[r] = v.x; fb.y1[r] = v.y; fb.x2[r] = v.z; fb.y2[r] = v.w; fb.kp[r] = 1;
        }
        __syncthreads();
        for (int i = 0; i < M; ++i) {
            if (fb.kp[i]) {
                float ax1 = fb.x1[i], ay1 = fb.y1[i], ax2 = fb.x2[i], ay2 = fb.y2[i];
                float aa = (ax2 - ax1) * (ay2 - ay1);
                for (int r = i + 1 + tid; r < M; r += 256) {
                    float bx1 = fb.x1[r], by1 = fb.y1[r], bx2 = fb.x2[r], by2 = fb.y2[r];
                    float ab = (bx2 - bx1) * (by2 - by1);
                    float ltx = fmaxf(ax1, bx1), lty = fmaxf(ay1, by1);
                    float rbx = fminf(ax2, bx2), rby = fminf(ay2, by2);
                    float ww = fmaxf(rbx - ltx, 0.0f), hh = fmaxf(rby - lty, 0.0f);
                    float inter = ww * hh;
                    float denom = ((aa + ab) - inter) + 1e-9f;
                    if ((inter / denom) > IOU_T) fb.kp[r] = 0;
                }
            }
            __syncthreads();
        }
        if (tid == 0) {
            int c2 = 0;
            for (int r = 0; r < M && c2 < MAXDET; ++r)
                if (fb.kp[r]) wsDst[b * MAXDET + c2++] = wsSlot[b * SLOTS + r];
            wsKept[b] = c2;
        }
    }
}

// ================= kernel 5: output write =================
__global__ __launch_bounds__(256)
void out_kernel(const float* __restrict__ score, const int* __restrict__ wsKept,
                const unsigned long long* __restrict__ wsKey,
                const int* __restrict__ wsDst, float* __restrict__ out) {
    const int b = blockIdx.x;
    const int e = blockIdx.y * 256 + threadIdx.x;
    if (e >= MAXDET * OUTC) return;
    const int row = e / OUTC, c = e - row * OUTC;
    float v = 0.0f;
    if (row < wsKept[b]) {
        unsigned long long key = wsKey[b * SLOTS + wsDst[b * MAXDET + row]];
        int n = (int)((key >> 16) & 0xFFFFULL);
        int cls = (int)((key >> 8) & 0xFFULL);
        int hw = n / 5, t5 = n - hw * 5;
        const float* base = score + (size_t)b * 425 * HWSZ + (size_t)(t5 * 85) * HWSZ + hw;
        if (c < 4) {
            float x = base[0];
            float y = base[HWSZ];
            float w = base[2 * HWSZ];
            float h = base[3 * HWSZ];
            float wh2 = w * 0.5f, hh2 = h * 0.5f;
            v = (c == 0) ? (x - wh2) : (c == 1) ? (y - hh2)
              : (c == 2) ? (x + wh2) : (y + hh2);
        } else if (c == 4) {
            v = __uint_as_float((~(unsigned int)(key >> 32)) & 0x7FFFFFFFu);
        } else if (c == 5) {
            v = (float)cls;
        } else {
            v = base[(c - 1) * HWSZ];              // raw logits
        }
    }
    out[(size_t)b * MAXDET * OUTC + e] = v;
}

// ================= mid-tier fallback: round-3 fused sort+NMS (proven) =================
struct SM2 {
    union {
        unsigned long long keys[SLOTS];
        unsigned long long supMat[MCAP * NWP];
    } u;
    float sbx1[SLOTS], sby1[SLOTS], sbx2[SLOTS], sby2[SLOTS];
    unsigned short sortedSlot[SLOTS];
    unsigned char keepFB[SLOTS];
};

__global__ __launch_bounds__(1024)
void nms_mid_kernel(const int* __restrict__ wsCnt, const unsigned long long* __restrict__ wsKey,
                    const float4* __restrict__ wsBox, int* __restrict__ wsKept,
                    int* __restrict__ wsDst) {
    __shared__ SM2 s;
    const int b = blockIdx.x;
    const int tid = threadIdx.x;
    int M = wsCnt[b]; if (M > SLOTS) M = SLOTS;

    for (int i = tid; i < M; i += 1024) s.u.keys[i] = wsKey[b * SLOTS + i];
    __syncthreads();
    for (int vi = tid; vi < M; vi += 1024) {
        unsigned long long ki = s.u.keys[vi];
        int rank = 0;
        #pragma unroll 4
        for (int j = 0; j < M; ++j) rank += (s.u.keys[j] < ki) ? 1 : 0;
        s.sortedSlot[rank] = (unsigned short)vi;
    }
    __syncthreads();
    for (int r = tid; r < M; r += 1024) {
        float4 bx = wsBox[b * SLOTS + s.sortedSlot[r]];
        s.sbx1[r] = bx.x; s.sby1[r] = bx.y; s.sbx2[r] = bx.z; s.sby2[r] = bx.w;
    }
    __syncthreads();

    if (M <= MCAP) {
        const int NW = (M + 63) >> 6;
        const int wid = tid >> 6, lane = tid & 63;
        for (int t = wid; t < M * NW; t += 16) {
            int i = t / NW, w = t - i * NW;
            float ax1 = s.sbx1[i], ay1 = s.sby1[i], ax2 = s.sbx2[i], ay2 = s.sby2[i];
            float aa = (ax2 - ax1) * (ay2 - ay1);
            int j = (w << 6) + lane;
            bool sup = false;
            if (j < M && j > i) {
                float bx1 = s.sbx1[j], by1 = s.sby1[j], bx2 = s.sbx2[j], by2 = s.sby2[j];
                float ab = (bx2 - bx1) * (by2 - by1);
                float ltx = fmaxf(ax1, bx1), lty = fmaxf(ay1, by1);
                float rbx = fminf(ax2, bx2), rby = fminf(ay2, by2);
                float ww = fmaxf(rbx - ltx, 0.0f), hh = fmaxf(rby - lty, 0.0f);
                float inter = ww * hh;
                float denom = ((aa + ab) - inter) + 1e-9f;
                sup = (inter / denom) > IOU_T;
            }
            unsigned long long mask = __ballot(sup);
            if (lane == 0) s.u.supMat[t] = mask;
        }
        __syncthreads();
        if (tid < 64) {
            const int lane = tid;
            unsigned long long keepW = 0;
            int rem = M - (lane << 6);
            if (rem >= 64) keepW = ~0ULL; else if (rem > 0) keepW = (~0ULL) >> (64 - rem);
            unsigned long long supA = (lane < NW && M > 0) ? s.u.supMat[lane] : 0ULL;
            unsigned long long supB = (lane < NW && M > 1) ? s.u.supMat[NW + lane] : 0ULL;
            int cnt = 0;
            for (int i = 0; i < M; ++i) {
                unsigned long long supN =
                    (lane < NW && (i + 2) < M) ? s.u.supMat[(i + 2) * NW + lane] : 0ULL;
                unsigned long long wv = __shfl(keepW, i >> 6, 64);
                if ((wv >> (i & 63)) & 1ULL) {
                    keepW &= ~supA;
                    if (lane == 0 && cnt < MAXDET) wsDst[b * MAXDET + cnt] = s.sortedSlot[i];
                    cnt++;
                }
                supA = supB; supB = supN;
            }
            if (lane == 0) wsKept[b] = (cnt < MAXDET) ? cnt : MAXDET;
        }
    } else {
        for (int r = tid; r < M; r += 1024) s.keepFB[r] = 1;
        __syncthreads();
        for (int i = 0; i < M; ++i) {
            if (s.keepFB[i]) {
                float ax1 = s.sbx1[i], ay1 = s.sby1[i], ax2 = s.sbx2[i], ay2 = s.sby2[i];
                float aa = (ax2 - ax1) * (ay2 - ay1);
                for (int r = i + 1 + tid; r < M; r += 1024) {
                    float bx1 = s.sbx1[r], by1 = s.sby1[r], bx2 = s.sbx2[r], by2 = s.sby2[r];
                    float ab = (bx2 - bx1) * (by2 - by1);
                    float ltx = fmaxf(ax1, bx1), lty = fmaxf(ay1, by1);
                    float rbx = fminf(ax2, bx2), rby = fminf(ay2, by2);
                    float ww = fmaxf(rbx - ltx, 0.0f), hh = fmaxf(rby - lty, 0.0f);
                    float inter = ww * hh;
                    float denom = ((aa + ab) - inter) + 1e-9f;
                    if ((inter / denom) > IOU_T) s.keepFB[r] = 0;
                }
            }
            __syncthreads();
        }
        if (tid == 0) {
            int cnt = 0;
            for (int r = 0; r < M && cnt < MAXDET; ++r)
                if (s.keepFB[r]) wsDst[b * MAXDET + cnt++] = s.sortedSlot[r];
            wsKept[b] = cnt;
        }
    }
}

// ================= last-resort fallback: round-2 single kernel (proven) =================
struct SMemFB {
    float bx1[NPRED], by1[NPRED], bx2[NPRED], by2[NPRED], area[NPRED];
    unsigned short sortedN[NPRED];
    union {
        unsigned long long vkey[NPRED];
        struct { float confR[MAXDET]; unsigned char jclsR[MAXDET]; } oi;
        unsigned char keepFB[NPRED];
    } u;
    unsigned short dstN[MAXDET];
    int validCount;
    int keptCount;
};

__device__ __forceinline__ void conf_argmax(const float* __restrict__ base, float obj,
                                            float& conf, int& bj) {
    float best = -INFINITY; int bjj = 0;
    #pragma unroll 8
    for (int k = 0; k < NCLS; ++k) {
        float v = base[(5 + k) * HWSZ] * obj;
        if (v > best) { best = v; bjj = k; }
    }
    conf = best; bj = bjj;
}

__global__ __launch_bounds__(1024)
void yolo_nms_single(const float* __restrict__ score, float* __restrict__ out) {
    __shared__ SMemFB s;
    const int b = blockIdx.x;
    const int tid = threadIdx.x;
    const float* sb = score + (size_t)b * 425 * HWSZ;
    if (tid == 0) s.validCount = 0;
    __syncthreads();
    for (int ci = tid; ci < NPRED; ci += 1024) {
        int t5 = ci / HWSZ;
        int hw = ci - t5 * HWSZ;
        int n = hw * 5 + t5;
        const float* base = sb + (size_t)(t5 * 85) * HWSZ + hw;
        float x = base[0], y = base[HWSZ], w = base[2 * HWSZ], h = base[3 * HWSZ];
        float obj = base[4 * HWSZ];
        float conf; int bj;
        conf_argmax(base, obj, conf, bj);
        bool valid = (obj > CONF_T) && (conf > CONF_T);
        float wh2 = w * 0.5f, hh2 = h * 0.5f;
        float x1 = x - wh2, y1 = y - hh2, x2 = x + wh2, y2 = y + hh2;
        float off = (float)bj * MAX_WH;
        float ox1 = x1 + off, oy1 = y1 + off, ox2 = x2 + off, oy2 = y2 + off;
        s.bx1[n] = ox1; s.by1[n] = oy1; s.bx2[n] = ox2; s.by2[n] = oy2;
        s.area[n] = (ox2 - ox1) * (oy2 - oy1);
        if (valid) {
            int slot = atomicAdd(&s.validCount, 1);
            unsigned int uu = __float_as_uint(conf);
            unsigned int desc = ~(uu | 0x80000000u);
            s.u.vkey[slot] = ((unsigned long long)desc << 32) | (unsigned int)n;
        }
    }
    __syncthreads();
    const int M = s.validCount;
    for (int vi = tid; vi < M; vi += 1024) {
        unsigned long long ki = s.u.vkey[vi];
        int rank = 0;
        for (int j = 0; j < M; ++j) rank += (s.u.vkey[j] < ki) ? 1 : 0;
        s.sortedN[rank] = (unsigned short)(ki & 0xFFFFULL);
    }
    __syncthreads();
    for (int r = tid; r < M; r += 1024) s.u.keepFB[r] = 1;
    __syncthreads();
    for (int i = 0; i < M; ++i) {
        if (s.u.keepFB[i]) {
            int ni = s.sortedN[i];
            float ax1 = s.bx1[ni], ay1 = s.by1[ni], ax2 = s.bx2[ni], ay2 = s.by2[ni];
            float aa = s.area[ni];
            for (int r = i + 1 + tid; r < M; r += 1024) {
                int nj = s.sortedN[r];
                float ltx = fmaxf(ax1, s.bx1[nj]);
                float lty = fmaxf(ay1, s.by1[nj]);
                float rbx = fminf(ax2, s.bx2[nj]);
                float rby = fminf(ay2, s.by2[nj]);
                float ww = fmaxf(rbx - ltx, 0.0f);
                float hh = fmaxf(rby - lty, 0.0f);
                float inter = ww * hh;
                float denom = ((aa + s.area[nj]) - inter) + 1e-9f;
                if ((inter / denom) > IOU_T) s.u.keepFB[r] = 0;
            }
        }
        __syncthreads();
    }
    if (tid == 0) {
        int cnt = 0;
        for (int r = 0; r < M && cnt < MAXDET; ++r)
            if (s.u.keepFB[r]) s.dstN[cnt++] = s.sortedN[r];
        s.keptCount = cnt;
    }
    __syncthreads();
    const int cnt = s.keptCount;
    if (tid < cnt) {
        int n = s.dstN[tid];
        int hw = n / 5, t5 = n - hw * 5;
        const float* base = sb + (size_t)(t5 * 85) * HWSZ + hw;
        float obj = base[4 * HWSZ];
        float conf; int bj;
        conf_argmax(base, obj, conf, bj);
        s.u.oi.confR[tid] = conf;
        s.u.oi.jclsR[tid] = (unsigned char)bj;
    }
    __syncthreads();
    float* ob = out + (size_t)b * MAXDET * OUTC;
    for (int e = tid; e < MAXDET * OUTC; e += 1024) {
        int row = e / OUTC, c = e - row * OUTC;
        float v = 0.0f;
        if (row < cnt) {
            int n = s.dstN[row];
            int hw = n / 5, t5 = n - hw * 5;
            const float* base = sb + (size_t)(t5 * 85) * HWSZ + hw;
            if (c < 4) {
                float x = base[0], y = base[HWSZ], w = base[2 * HWSZ], h = base[3 * HWSZ];
                float wh2 = w * 0.5f, hh2 = h * 0.5f;
                v = (c == 0) ? (x - wh2) : (c == 1) ? (y - hh2)
                  : (c == 2) ? (x + wh2) : (y + hh2);
            } else if (c == 4) {
                v = s.u.oi.confR[row];
            } else if (c == 5) {
                v = (float)s.u.oi.jclsR[row];
            } else {
                v = base[(c - 1) * HWSZ];
            }
        }
        ob[e] = v;
    }
}

extern "C" void kernel_launch(void* const* d_in, const int* in_sizes, int n_in,
                              void* d_out, int out_size, void* d_ws, size_t ws_size,
                              hipStream_t stream) {
    const float* score = (const float*)d_in[0];
    float* out = (float*)d_out;
    char* ws = (char*)d_ws;
    int* wsCnt = (int*)ws;
    int* wsKept = (int*)(ws + OFF_KEPT);
    unsigned long long* wsKey = (unsigned long long*)(ws + OFF_KEY);
    float4* wsBox = (float4*)(ws + OFF_BOX);
    int* wsDst = (int*)(ws + OFF_DST);
    int* wsSlot = (int*)(ws + OFF_SLOT);
    float4* wsSBox = (float4*)(ws + OFF_SBOX);
    unsigned long long* supMat = (unsigned long long*)(ws + OFF_SUP);

    if (ws_size >= (size_t)WS_FULL) {
        hipMemsetAsync(ws, 0, 256, stream);
        prep_kernel<<<dim3(NIMG, 12), 128, 0, stream>>>(score, wsCnt, wsKey, wsBox);
        sort_kernel<<<NIMG, 1024, 0, stream>>>(wsCnt, wsKey, wsBox, wsSlot, wsSBox);
        supmat_kernel<<<dim3(NIMG, NWP), 512, 0, stream>>>(wsCnt, wsSBox, supMat);
        scan_kernel<<<NIMG, 256, 0, stream>>>(wsCnt, supMat, wsSlot, wsSBox, wsKept, wsDst);
        out_kernel<<<dim3(NIMG, 101), 256, 0, stream>>>(score, wsKept, wsKey, wsDst, out);
    } else if (ws_size >= (size_t)WS_MID) {
        hipMemsetAsync(ws, 0, 256, stream);
        prep_kernel<<<dim3(NIMG, 12), 128, 0, stream>>>(score, wsCnt, wsKey, wsBox);
        nms_mid_kernel<<<NIMG, 1024, 0, stream>>>(wsCnt, wsKey, wsBox, wsKept, wsDst);
        out_kernel<<<dim3(NIMG, 101), 256, 0, stream>>>(score, wsKept, wsKey, wsDst, out);
    } else {
        yolo_nms_single<<<NIMG, 1024, 0, stream>>>(score, out);
    }
}

// Round 5
// 95.211 us; speedup vs baseline: 3.7451x; 1.1406x over previous
//
#include <hip/hip_runtime.h>

#define NPRED 1445
#define NCLS  80
#define MAXDET 300
#define OUTC  86
#define CONF_T 0.6f
#define IOU_T  0.45f
#define MAX_WH 4096.0f
#define HWSZ  289
#define NIMG  32
#define SLOTS 768      // ws slots per image (M mean ~396, sigma ~17)
#define MCAP  512      // fast-path cap (~7 sigma)
#define NWP   8        // MCAP/64 words per suppression row

// ---- d_ws layout (bytes) ----
#define OFF_KEPT 128        // int[32]
#define OFF_KEY  256        // u64[32][SLOTS]  (after sort_kernel: rank-sorted)
#define OFF_BOX  196864     // float4[32][SLOTS]   (unsorted, by slot)
#define OFF_DST  590080     // int[32][MAXDET]     (RANK per kept output row)
#define OFF_SLOT 628480     // (unused, kept for layout stability)
#define OFF_SBOX 726784     // float4[32][SLOTS]   (rank-sorted boxes)
#define OFF_SUP  1120000    // u64[32][MCAP][NWP]  (suppression bitmask rows)
#define WS_FULL  2168576
#define WS_MID   628480

__device__ __forceinline__ unsigned long long bcast64(unsigned long long v, int srcLane) {
    unsigned lo = (unsigned)__builtin_amdgcn_readlane((int)(unsigned)(v & 0xFFFFFFFFULL), srcLane);
    unsigned hi = (unsigned)__builtin_amdgcn_readlane((int)(unsigned)(v >> 32), srcLane);
    return ((unsigned long long)hi << 32) | lo;
}

// ================= kernel 1: per-candidate prep =================
__global__ __launch_bounds__(128)
void prep_kernel(const float* __restrict__ score, int* __restrict__ wsCnt,
                 unsigned long long* __restrict__ wsKey, float4* __restrict__ wsBox) {
    const int b = blockIdx.x;
    const int ci = blockIdx.y * 128 + threadIdx.x;
    if (ci >= NPRED) return;
    const int t5 = ci / HWSZ;
    const int hw = ci - t5 * HWSZ;
    const int n = hw * 5 + t5;                     // candidate row in x[N][85]
    const float* base = score + (size_t)b * 425 * HWSZ + (size_t)(t5 * 85) * HWSZ + hw;
    float x = base[0];
    float y = base[HWSZ];
    float w = base[2 * HWSZ];
    float h = base[3 * HWSZ];
    float obj = base[4 * HWSZ];

    float best = -INFINITY; int bj = 0;
    #pragma unroll 16
    for (int k = 0; k < NCLS; ++k) {
        float v = base[(5 + k) * HWSZ] * obj;      // cls = logits * obj
        if (v > best) { best = v; bj = k; }        // strict >: first-occurrence argmax
    }
    if (!((obj > CONF_T) && (best > CONF_T))) return;

    float wh2 = w * 0.5f, hh2 = h * 0.5f;
    float x1 = x - wh2, y1 = y - hh2, x2 = x + wh2, y2 = y + hh2;
    float off = (float)bj * MAX_WH;                // exact product
    int slot = atomicAdd(&wsCnt[b], 1);
    if (slot >= SLOTS) return;
    unsigned int u = __float_as_uint(best);        // conf > 0.6 -> positive
    unsigned int desc = ~(u | 0x80000000u);        // ascending u64 == descending conf
    wsKey[b * SLOTS + slot] = ((unsigned long long)desc << 32)
                            | ((unsigned long long)(unsigned)n << 16)
                            | ((unsigned long long)(unsigned)bj << 8);
    wsBox[b * SLOTS + slot] = make_float4(x1 + off, y1 + off, x2 + off, y2 + off);
}

// ================= kernel 2: rank-count sort (in-place key permute) =================
__global__ __launch_bounds__(1024)
void sort_kernel(const int* __restrict__ wsCnt, unsigned long long* __restrict__ wsKey,
                 const float4* __restrict__ wsBox, float4* __restrict__ wsSBox) {
    __shared__ unsigned long long keys[SLOTS];
    const int b = blockIdx.x, tid = threadIdx.x;
    int M = wsCnt[b]; if (M > SLOTS) M = SLOTS;
    for (int i = tid; i < M; i += 1024) keys[i] = wsKey[b * SLOTS + i];
    __syncthreads();
    if (tid < M) {                                 // M <= 768 < 1024: one key/thread
        unsigned long long ki = keys[tid];
        int rank = 0;
        #pragma unroll 4
        for (int j = 0; j < M; ++j) rank += (keys[j] < ki) ? 1 : 0;   // unique keys
        wsKey[b * SLOTS + rank] = ki;              // rank-sorted keys (LDS snapshot safe)
        wsSBox[b * SLOTS + rank] = wsBox[b * SLOTS + tid];
    }
}

// ================= kernel 3: suppression bitmask matrix =================
// grid (NIMG, NWP); block (b,w) computes word w of every row i (256 CUs busy)
__global__ __launch_bounds__(512)
void supmat_kernel(const int* __restrict__ wsCnt, const float4* __restrict__ wsSBox,
                   unsigned long long* __restrict__ supMat) {
    const int b = blockIdx.x, w = blockIdx.y, tid = threadIdx.x;
    int M = wsCnt[b]; if (M > SLOTS) M = SLOTS;
    if (M > MCAP) return;                          // fallback path handles
    __shared__ float4 box[MCAP];
    for (int r = tid; r < M; r += 512) box[r] = wsSBox[b * SLOTS + r];
    __syncthreads();
    const int lane = tid & 63, wid = tid >> 6;
    const int j = (w << 6) + lane;
    float4 jb = make_float4(0.f, 0.f, 0.f, 0.f); float ab = 0.f;
    const bool jok = (j < M);
    if (jok) { jb = box[j]; ab = (jb.z - jb.x) * (jb.w - jb.y); }
    unsigned long long* rowBase = supMat + ((size_t)b * MCAP) * NWP + w;
    if (wid >= M) return;
    float4 nxt = box[wid];
    for (int i = wid; i < M; i += 8) {
        float4 cur = nxt;
        int nx = i + 8; if (nx < M) nxt = box[nx];   // depth-1 prefetch
        float aa = (cur.z - cur.x) * (cur.w - cur.y);
        bool sup = false;
        if (jok && j > i) {
            float ltx = fmaxf(cur.x, jb.x), lty = fmaxf(cur.y, jb.y);
            float rbx = fminf(cur.z, jb.z), rby = fminf(cur.w, jb.w);
            float ww = fmaxf(rbx - ltx, 0.0f), hh = fmaxf(rby - lty, 0.0f);
            float inter = ww * hh;
            float denom = ((aa + ab) - inter) + 1e-9f;   // left-to-right, exact div
            sup = (inter / denom) > IOU_T;
        }
        unsigned long long mask = __ballot(sup);
        if (lane == 0) rowBase[(size_t)i * NWP] = mask;  // every (i<M, w) written
    }
}

// ================= kernel 4: greedy scan (1 wave, rank stores, triple prefetch) =================
__global__ __launch_bounds__(256)
void scan_kernel(const int* __restrict__ wsCnt, const unsigned long long* __restrict__ supMat,
                 const float4* __restrict__ wsSBox,
                 int* __restrict__ wsKept, int* __restrict__ wsDst) {
    __shared__ struct {
        float x1[SLOTS], y1[SLOTS], x2[SLOTS], y2[SLOTS];
        unsigned char kp[SLOTS];
    } fb;
    const int b = blockIdx.x, tid = threadIdx.x;
    int M = wsCnt[b]; if (M > SLOTS) M = SLOTS;

    if (M <= MCAP) {
        if (tid >= 64) return;                      // single wave; no barriers here
        const int lane = tid;
        unsigned long long keepW = 0ULL;
        int rem = M - (lane << 6);
        if (rem >= 64) keepW = ~0ULL; else if (rem > 0) keepW = (~0ULL) >> (64 - rem);
        const unsigned long long* rows = supMat + ((size_t)b * MCAP) * NWP;
        const bool ld = (lane < NWP);
        unsigned long long A[8], B[8], C[8];
        int cnt = 0; bool done = false;
#define LOADB(buf, bs) { _Pragma("unroll") for (int k = 0; k < 8; ++k) { \
        int ii = (bs) + k; buf[k] = (ld && ii < M) ? rows[(size_t)ii * NWP + lane] : 0ULL; } }
#define PROCB(buf, bs) { _Pragma("unroll") for (int k = 0; k < 8; ++k) { \
        int ii = (bs) + k; \
        if (!done && ii < M) { \
            unsigned long long w64 = bcast64(keepW, ii >> 6); \
            if ((w64 >> (ii & 63)) & 1ULL) { \
                keepW &= ~buf[k]; \
                if (lane == 0) wsDst[b * MAXDET + cnt] = ii;  /* store RANK: no load */ \
                ++cnt; \
                if (cnt == MAXDET) done = true;   /* later bits can't reach rank<300 */ \
            } } } }
        LOADB(A, 0)
        LOADB(B, 8)
        for (int base = 0; base < M && !done; base += 24) {
            LOADB(C, base + 16)
            PROCB(A, base)
            LOADB(A, base + 24)
            PROCB(B, base + 8)
            LOADB(B, base + 32)
            PROCB(C, base + 16)
        }
#undef LOADB
#undef PROCB
        if (lane == 0) wsKept[b] = cnt;
    } else {
        // ---- fallback (M > MCAP, ~0 probability): barrier-serial greedy ----
        for (int r = tid; r < M; r += 256) {
            float4 v = wsSBox[b * SLOTS + r];
            fb.x1[r] = v.x; fb.y1[r] = v.y; fb.x2[r] = v.z; fb.y2[r] = v.w; fb.kp[r] = 1;
        }
        __syncthreads();
        for (int i = 0; i < M; ++i) {
            if (fb.kp[i]) {
                float ax1 = fb.x1[i], ay1 = fb.y1[i], ax2 = fb.x2[i], ay2 = fb.y2[i];
                float aa = (ax2 - ax1) * (ay2 - ay1);
                for (int r = i + 1 + tid; r < M; r += 256) {
                    float bx1 = fb.x1[r], by1 = fb.y1[r], bx2 = fb.x2[r], by2 = fb.y2[r];
                    float ab = (bx2 - bx1) * (by2 - by1);
                    float ltx = fmaxf(ax1, bx1), lty = fmaxf(ay1, by1);
                    float rbx = fminf(ax2, bx2), rby = fminf(ay2, by2);
                    float ww = fmaxf(rbx - ltx, 0.0f), hh = fmaxf(rby - lty, 0.0f);
                    float inter = ww * hh;
                    float denom = ((aa + ab) - inter) + 1e-9f;
                    if ((inter / denom) > IOU_T) fb.kp[r] = 0;
                }
            }
            __syncthreads();
        }
        if (tid == 0) {
            int c2 = 0;
            for (int r = 0; r < M && c2 < MAXDET; ++r)
                if (fb.kp[r]) wsDst[b * MAXDET + c2++] = r;    // store RANK
            wsKept[b] = c2;
        }
    }
}

// ================= kernel 5: output write =================
__global__ __launch_bounds__(256)
void out_kernel(const float* __restrict__ score, const int* __restrict__ wsKept,
                const unsigned long long* __restrict__ wsKey,   // rank-sorted
                const int* __restrict__ wsDst, float* __restrict__ out) {
    const int b = blockIdx.x;
    const int e = blockIdx.y * 256 + threadIdx.x;
    if (e >= MAXDET * OUTC) return;
    const int row = e / OUTC, c = e - row * OUTC;
    float v = 0.0f;
    if (row < wsKept[b]) {
        unsigned long long key = wsKey[b * SLOTS + wsDst[b * MAXDET + row]];
        int n = (int)((key >> 16) & 0xFFFFULL);
        int cls = (int)((key >> 8) & 0xFFULL);
        int hw = n / 5, t5 = n - hw * 5;
        const float* base = score + (size_t)b * 425 * HWSZ + (size_t)(t5 * 85) * HWSZ + hw;
        if (c < 4) {
            float x = base[0];
            float y = base[HWSZ];
            float w = base[2 * HWSZ];
            float h = base[3 * HWSZ];
            float wh2 = w * 0.5f, hh2 = h * 0.5f;
            v = (c == 0) ? (x - wh2) : (c == 1) ? (y - hh2)
              : (c == 2) ? (x + wh2) : (y + hh2);
        } else if (c == 4) {
            v = __uint_as_float((~(unsigned int)(key >> 32)) & 0x7FFFFFFFu);
        } else if (c == 5) {
            v = (float)cls;
        } else {
            v = base[(c - 1) * HWSZ];              // raw logits
        }
    }
    out[(size_t)b * MAXDET * OUTC + e] = v;
}

// ================= mid-tier fallback: fused sort+NMS (proven structure) =================
struct SM2 {
    union {
        unsigned long long keys[SLOTS];
        unsigned long long supMat[MCAP * NWP];
    } u;
    float sbx1[SLOTS], sby1[SLOTS], sbx2[SLOTS], sby2[SLOTS];
    unsigned short sortedSlot[SLOTS];
    unsigned char keepFB[SLOTS];
};

__global__ __launch_bounds__(1024)
void nms_mid_kernel(const int* __restrict__ wsCnt, unsigned long long* __restrict__ wsKey,
                    const float4* __restrict__ wsBox, int* __restrict__ wsKept,
                    int* __restrict__ wsDst) {
    __shared__ SM2 s;
    const int b = blockIdx.x;
    const int tid = threadIdx.x;
    int M = wsCnt[b]; if (M > SLOTS) M = SLOTS;

    for (int i = tid; i < M; i += 1024) s.u.keys[i] = wsKey[b * SLOTS + i];
    __syncthreads();
    for (int vi = tid; vi < M; vi += 1024) {
        unsigned long long ki = s.u.keys[vi];
        int rank = 0;
        #pragma unroll 4
        for (int j = 0; j < M; ++j) rank += (s.u.keys[j] < ki) ? 1 : 0;
        s.sortedSlot[rank] = (unsigned short)vi;
    }
    __syncthreads();
    for (int r = tid; r < M; r += 1024) {
        int slot = s.sortedSlot[r];
        float4 bx = wsBox[b * SLOTS + slot];
        s.sbx1[r] = bx.x; s.sby1[r] = bx.y; s.sbx2[r] = bx.z; s.sby2[r] = bx.w;
        wsKey[b * SLOTS + r] = s.u.keys[slot];     // rank-sorted writeback for out_kernel
    }
    __syncthreads();

    if (M <= MCAP) {
        const int NW = (M + 63) >> 6;
        const int wid = tid >> 6, lane = tid & 63;
        for (int t = wid; t < M * NW; t += 16) {
            int i = t / NW, w = t - i * NW;
            float ax1 = s.sbx1[i], ay1 = s.sby1[i], ax2 = s.sbx2[i], ay2 = s.sby2[i];
            float aa = (ax2 - ax1) * (ay2 - ay1);
            int j = (w << 6) + lane;
            bool sup = false;
            if (j < M && j > i) {
                float bx1 = s.sbx1[j], by1 = s.sby1[j], bx2 = s.sbx2[j], by2 = s.sby2[j];
                float ab = (bx2 - bx1) * (by2 - by1);
                float ltx = fmaxf(ax1, bx1), lty = fmaxf(ay1, by1);
                float rbx = fminf(ax2, bx2), rby = fminf(ay2, by2);
                float ww = fmaxf(rbx - ltx, 0.0f), hh = fmaxf(rby - lty, 0.0f);
                float inter = ww * hh;
                float denom = ((aa + ab) - inter) + 1e-9f;
                sup = (inter / denom) > IOU_T;
            }
            unsigned long long mask = __ballot(sup);
            if (lane == 0) s.u.supMat[t] = mask;
        }
        __syncthreads();
        if (tid < 64) {
            const int lane = tid;
            unsigned long long keepW = 0;
            int rem = M - (lane << 6);
            if (rem >= 64) keepW = ~0ULL; else if (rem > 0) keepW = (~0ULL) >> (64 - rem);
            unsigned long long supA = (lane < NW && M > 0) ? s.u.supMat[lane] : 0ULL;
            unsigned long long supB = (lane < NW && M > 1) ? s.u.supMat[NW + lane] : 0ULL;
            int cnt = 0;
            for (int i = 0; i < M; ++i) {
                unsigned long long supN =
                    (lane < NW && (i + 2) < M) ? s.u.supMat[(i + 2) * NW + lane] : 0ULL;
                unsigned long long wv = __shfl(keepW, i >> 6, 64);
                if ((wv >> (i & 63)) & 1ULL) {
                    keepW &= ~supA;
                    if (lane == 0 && cnt < MAXDET) wsDst[b * MAXDET + cnt] = i;  // RANK
                    cnt++;
                }
                supA = supB; supB = supN;
            }
            if (lane == 0) wsKept[b] = (cnt < MAXDET) ? cnt : MAXDET;
        }
    } else {
        for (int r = tid; r < M; r += 1024) s.keepFB[r] = 1;
        __syncthreads();
        for (int i = 0; i < M; ++i) {
            if (s.keepFB[i]) {
                float ax1 = s.sbx1[i], ay1 = s.sby1[i], ax2 = s.sbx2[i], ay2 = s.sby2[i];
                float aa = (ax2 - ax1) * (ay2 - ay1);
                for (int r = i + 1 + tid; r < M; r += 1024) {
                    float bx1 = s.sbx1[r], by1 = s.sby1[r], bx2 = s.sbx2[r], by2 = s.sby2[r];
                    float ab = (bx2 - bx1) * (by2 - by1);
                    float ltx = fmaxf(ax1, bx1), lty = fmaxf(ay1, by1);
                    float rbx = fminf(ax2, bx2), rby = fminf(ay2, by2);
                    float ww = fmaxf(rbx - ltx, 0.0f), hh = fmaxf(rby - lty, 0.0f);
                    float inter = ww * hh;
                    float denom = ((aa + ab) - inter) + 1e-9f;
                    if ((inter / denom) > IOU_T) s.keepFB[r] = 0;
                }
            }
            __syncthreads();
        }
        if (tid == 0) {
            int cnt = 0;
            for (int r = 0; r < M && cnt < MAXDET; ++r)
                if (s.keepFB[r]) wsDst[b * MAXDET + cnt++] = r;  // RANK
            wsKept[b] = cnt;
        }
    }
}

// ================= last-resort fallback: round-2 single kernel (proven) =================
struct SMemFB {
    float bx1[NPRED], by1[NPRED], bx2[NPRED], by2[NPRED], area[NPRED];
    unsigned short sortedN[NPRED];
    union {
        unsigned long long vkey[NPRED];
        struct { float confR[MAXDET]; unsigned char jclsR[MAXDET]; } oi;
        unsigned char keepFB[NPRED];
    } u;
    unsigned short dstN[MAXDET];
    int validCount;
    int keptCount;
};

__device__ __forceinline__ void conf_argmax(const float* __restrict__ base, float obj,
                                            float& conf, int& bj) {
    float best = -INFINITY; int bjj = 0;
    #pragma unroll 8
    for (int k = 0; k < NCLS; ++k) {
        float v = base[(5 + k) * HWSZ] * obj;
        if (v > best) { best = v; bjj = k; }
    }
    conf = best; bj = bjj;
}

__global__ __launch_bounds__(1024)
void yolo_nms_single(const float* __restrict__ score, float* __restrict__ out) {
    __shared__ SMemFB s;
    const int b = blockIdx.x;
    const int tid = threadIdx.x;
    const float* sb = score + (size_t)b * 425 * HWSZ;
    if (tid == 0) s.validCount = 0;
    __syncthreads();
    for (int ci = tid; ci < NPRED; ci += 1024) {
        int t5 = ci / HWSZ;
        int hw = ci - t5 * HWSZ;
        int n = hw * 5 + t5;
        const float* base = sb + (size_t)(t5 * 85) * HWSZ + hw;
        float x = base[0], y = base[HWSZ], w = base[2 * HWSZ], h = base[3 * HWSZ];
        float obj = base[4 * HWSZ];
        float conf; int bj;
        conf_argmax(base, obj, conf, bj);
        bool valid = (obj > CONF_T) && (conf > CONF_T);
        float wh2 = w * 0.5f, hh2 = h * 0.5f;
        float x1 = x - wh2, y1 = y - hh2, x2 = x + wh2, y2 = y + hh2;
        float off = (float)bj * MAX_WH;
        float ox1 = x1 + off, oy1 = y1 + off, ox2 = x2 + off, oy2 = y2 + off;
        s.bx1[n] = ox1; s.by1[n] = oy1; s.bx2[n] = ox2; s.by2[n] = oy2;
        s.area[n] = (ox2 - ox1) * (oy2 - oy1);
        if (valid) {
            int slot = atomicAdd(&s.validCount, 1);
            unsigned int uu = __float_as_uint(conf);
            unsigned int desc = ~(uu | 0x80000000u);
            s.u.vkey[slot] = ((unsigned long long)desc << 32) | (unsigned int)n;
        }
    }
    __syncthreads();
    const int M = s.validCount;
    for (int vi = tid; vi < M; vi += 1024) {
        unsigned long long ki = s.u.vkey[vi];
        int rank = 0;
        for (int j = 0; j < M; ++j) rank += (s.u.vkey[j] < ki) ? 1 : 0;
        s.sortedN[rank] = (unsigned short)(ki & 0xFFFFULL);
    }
    __syncthreads();
    for (int r = tid; r < M; r += 1024) s.u.keepFB[r] = 1;
    __syncthreads();
    for (int i = 0; i < M; ++i) {
        if (s.u.keepFB[i]) {
            int ni = s.sortedN[i];
            float ax1 = s.bx1[ni], ay1 = s.by1[ni], ax2 = s.bx2[ni], ay2 = s.by2[ni];
            float aa = s.area[ni];
            for (int r = i + 1 + tid; r < M; r += 1024) {
                int nj = s.sortedN[r];
                float ltx = fmaxf(ax1, s.bx1[nj]);
                float lty = fmaxf(ay1, s.by1[nj]);
                float rbx = fminf(ax2, s.bx2[nj]);
                float rby = fminf(ay2, s.by2[nj]);
                float ww = fmaxf(rbx - ltx, 0.0f);
                float hh = fmaxf(rby - lty, 0.0f);
                float inter = ww * hh;
                float denom = ((aa + s.area[nj]) - inter) + 1e-9f;
                if ((inter / denom) > IOU_T) s.u.keepFB[r] = 0;
            }
        }
        __syncthreads();
    }
    if (tid == 0) {
        int cnt = 0;
        for (int r = 0; r < M && cnt < MAXDET; ++r)
            if (s.u.keepFB[r]) s.dstN[cnt++] = s.sortedN[r];
        s.keptCount = cnt;
    }
    __syncthreads();
    const int cnt = s.keptCount;
    if (tid < cnt) {
        int n = s.dstN[tid];
        int hw = n / 5, t5 = n - hw * 5;
        const float* base = sb + (size_t)(t5 * 85) * HWSZ + hw;
        float obj = base[4 * HWSZ];
        float conf; int bj;
        conf_argmax(base, obj, conf, bj);
        s.u.oi.confR[tid] = conf;
        s.u.oi.jclsR[tid] = (unsigned char)bj;
    }
    __syncthreads();
    float* ob = out + (size_t)b * MAXDET * OUTC;
    for (int e = tid; e < MAXDET * OUTC; e += 1024) {
        int row = e / OUTC, c = e - row * OUTC;
        float v = 0.0f;
        if (row < cnt) {
            int n = s.dstN[row];
            int hw = n / 5, t5 = n - hw * 5;
            const float* base = sb + (size_t)(t5 * 85) * HWSZ + hw;
            if (c < 4) {
                float x = base[0], y = base[HWSZ], w = base[2 * HWSZ], h = base[3 * HWSZ];
                float wh2 = w * 0.5f, hh2 = h * 0.5f;
                v = (c == 0) ? (x - wh2) : (c == 1) ? (y - hh2)
                  : (c == 2) ? (x + wh2) : (y + hh2);
            } else if (c == 4) {
                v = s.u.oi.confR[row];
            } else if (c == 5) {
                v = (float)s.u.oi.jclsR[row];
            } else {
                v = base[(c - 1) * HWSZ];
            }
        }
        ob[e] = v;
    }
}

extern "C" void kernel_launch(void* const* d_in, const int* in_sizes, int n_in,
                              void* d_out, int out_size, void* d_ws, size_t ws_size,
                              hipStream_t stream) {
    const float* score = (const float*)d_in[0];
    float* out = (float*)d_out;
    char* ws = (char*)d_ws;
    int* wsCnt = (int*)ws;
    int* wsKept = (int*)(ws + OFF_KEPT);
    unsigned long long* wsKey = (unsigned long long*)(ws + OFF_KEY);
    float4* wsBox = (float4*)(ws + OFF_BOX);
    int* wsDst = (int*)(ws + OFF_DST);
    float4* wsSBox = (float4*)(ws + OFF_SBOX);
    unsigned long long* supMat = (unsigned long long*)(ws + OFF_SUP);

    if (ws_size >= (size_t)WS_FULL) {
        hipMemsetAsync(ws, 0, 256, stream);
        prep_kernel<<<dim3(NIMG, 12), 128, 0, stream>>>(score, wsCnt, wsKey, wsBox);
        sort_kernel<<<NIMG, 1024, 0, stream>>>(wsCnt, wsKey, wsBox, wsSBox);
        supmat_kernel<<<dim3(NIMG, NWP), 512, 0, stream>>>(wsCnt, wsSBox, supMat);
        scan_kernel<<<NIMG, 256, 0, stream>>>(wsCnt, supMat, wsSBox, wsKept, wsDst);
        out_kernel<<<dim3(NIMG, 101), 256, 0, stream>>>(score, wsKept, wsKey, wsDst, out);
    } else if (ws_size >= (size_t)WS_MID) {
        hipMemsetAsync(ws, 0, 256, stream);
        prep_kernel<<<dim3(NIMG, 12), 128, 0, stream>>>(score, wsCnt, wsKey, wsBox);
        nms_mid_kernel<<<NIMG, 1024, 0, stream>>>(wsCnt, wsKey, wsBox, wsKept, wsDst);
        out_kernel<<<dim3(NIMG, 101), 256, 0, stream>>>(score, wsKept, wsKey, wsDst, out);
    } else {
        yolo_nms_single<<<NIMG, 1024, 0, stream>>>(score, out);
    }
}

// Round 6
// 81.134 us; speedup vs baseline: 4.3949x; 1.1735x over previous
//
#include <hip/hip_runtime.h>

#define NPRED 1445
#define NCLS  80
#define MAXDET 300
#define OUTC  86
#define CONF_T 0.6f
#define IOU_T  0.45f
#define MAX_WH 4096.0f
#define HWSZ  289
#define NIMG  32
#define SLOTS 768      // ws slots per image (M mean ~396, sigma ~17)
#define MCAP  512      // fast-path cap (~7 sigma)
#define NWP   8        // MCAP/64 words per suppression row

// ---- d_ws layout (bytes) ----
#define OFF_KEPT 128        // int[32]
#define OFF_KEY  256        // u64[32][SLOTS]  (after sort_kernel: rank-sorted)
#define OFF_BOX  196864     // float4[32][SLOTS]   (unsorted, by slot)
#define OFF_DST  590080     // int[32][MAXDET]     (RANK per kept output row)
#define OFF_SLOT 628480     // (unused, kept for layout stability)
#define OFF_SBOX 726784     // float4[32][SLOTS]   (rank-sorted boxes)
#define OFF_SUP  1120000    // u64[32][MCAP][NWP]  (suppression bitmask rows)
#define WS_FULL  2168576
#define WS_MID   628480

__device__ __forceinline__ unsigned long long bcast64(unsigned long long v, int srcLane) {
    unsigned lo = (unsigned)__builtin_amdgcn_readlane((int)(unsigned)(v & 0xFFFFFFFFULL), srcLane);
    unsigned hi = (unsigned)__builtin_amdgcn_readlane((int)(unsigned)(v >> 32), srcLane);
    return ((unsigned long long)hi << 32) | lo;
}

// ================= kernel 1: per-candidate prep =================
__global__ __launch_bounds__(128)
void prep_kernel(const float* __restrict__ score, int* __restrict__ wsCnt,
                 unsigned long long* __restrict__ wsKey, float4* __restrict__ wsBox) {
    const int b = blockIdx.x;
    const int ci = blockIdx.y * 128 + threadIdx.x;
    if (ci >= NPRED) return;
    const int t5 = ci / HWSZ;
    const int hw = ci - t5 * HWSZ;
    const int n = hw * 5 + t5;                     // candidate row in x[N][85]
    const float* base = score + (size_t)b * 425 * HWSZ + (size_t)(t5 * 85) * HWSZ + hw;
    float x = base[0];
    float y = base[HWSZ];
    float w = base[2 * HWSZ];
    float h = base[3 * HWSZ];
    float obj = base[4 * HWSZ];

    float best = -INFINITY; int bj = 0;
    #pragma unroll 16
    for (int k = 0; k < NCLS; ++k) {
        float v = base[(5 + k) * HWSZ] * obj;      // cls = logits * obj
        if (v > best) { best = v; bj = k; }        // strict >: first-occurrence argmax
    }
    if (!((obj > CONF_T) && (best > CONF_T))) return;

    float wh2 = w * 0.5f, hh2 = h * 0.5f;
    float x1 = x - wh2, y1 = y - hh2, x2 = x + wh2, y2 = y + hh2;
    float off = (float)bj * MAX_WH;                // exact product
    int slot = atomicAdd(&wsCnt[b], 1);
    if (slot >= SLOTS) return;
    unsigned int u = __float_as_uint(best);        // conf > 0.6 -> positive
    unsigned int desc = ~(u | 0x80000000u);        // ascending u64 == descending conf
    wsKey[b * SLOTS + slot] = ((unsigned long long)desc << 32)
                            | ((unsigned long long)(unsigned)n << 16)
                            | ((unsigned long long)(unsigned)bj << 8);
    wsBox[b * SLOTS + slot] = make_float4(x1 + off, y1 + off, x2 + off, y2 + off);
}

// ================= kernel 2: rank-count sort (in-place key permute) =================
__global__ __launch_bounds__(1024)
void sort_kernel(const int* __restrict__ wsCnt, unsigned long long* __restrict__ wsKey,
                 const float4* __restrict__ wsBox, float4* __restrict__ wsSBox) {
    __shared__ unsigned long long keys[SLOTS];
    const int b = blockIdx.x, tid = threadIdx.x;
    int M = wsCnt[b]; if (M > SLOTS) M = SLOTS;
    for (int i = tid; i < M; i += 1024) keys[i] = wsKey[b * SLOTS + i];
    __syncthreads();
    if (tid < M) {                                 // M <= 768 < 1024: one key/thread
        unsigned long long ki = keys[tid];
        int rank = 0;
        #pragma unroll 4
        for (int j = 0; j < M; ++j) rank += (keys[j] < ki) ? 1 : 0;   // unique keys
        wsKey[b * SLOTS + rank] = ki;              // rank-sorted keys (LDS snapshot safe)
        wsSBox[b * SLOTS + rank] = wsBox[b * SLOTS + tid];
    }
}

// ================= kernel 3: suppression bitmask matrix =================
// grid (NIMG, NWP); block (b,w) computes word w of every row i (256 CUs busy)
__global__ __launch_bounds__(512)
void supmat_kernel(const int* __restrict__ wsCnt, const float4* __restrict__ wsSBox,
                   unsigned long long* __restrict__ supMat) {
    const int b = blockIdx.x, w = blockIdx.y, tid = threadIdx.x;
    int M = wsCnt[b]; if (M > SLOTS) M = SLOTS;
    if (M > MCAP) return;                          // fallback path handles
    __shared__ float4 box[MCAP];
    for (int r = tid; r < M; r += 512) box[r] = wsSBox[b * SLOTS + r];
    __syncthreads();
    const int lane = tid & 63, wid = tid >> 6;
    const int j = (w << 6) + lane;
    float4 jb = make_float4(0.f, 0.f, 0.f, 0.f); float ab = 0.f;
    const bool jok = (j < M);
    if (jok) { jb = box[j]; ab = (jb.z - jb.x) * (jb.w - jb.y); }
    unsigned long long* rowBase = supMat + ((size_t)b * MCAP) * NWP + w;
    if (wid >= M) return;
    float4 nxt = box[wid];
    for (int i = wid; i < M; i += 8) {
        float4 cur = nxt;
        int nx = i + 8; if (nx < M) nxt = box[nx];   // depth-1 prefetch
        float aa = (cur.z - cur.x) * (cur.w - cur.y);
        bool sup = false;
        if (jok && j > i) {
            float ltx = fmaxf(cur.x, jb.x), lty = fmaxf(cur.y, jb.y);
            float rbx = fminf(cur.z, jb.z), rby = fminf(cur.w, jb.w);
            float ww = fmaxf(rbx - ltx, 0.0f), hh = fmaxf(rby - lty, 0.0f);
            float inter = ww * hh;
            float denom = ((aa + ab) - inter) + 1e-9f;   // left-to-right, exact div
            sup = (inter / denom) > IOU_T;
        }
        unsigned long long mask = __ballot(sup);
        if (lane == 0) rowBase[(size_t)i * NWP] = mask;  // every (i<M, w) written
    }
}

// ================= kernel 4: greedy scan (LDS-staged supMat, 1-wave bit-scan) =================
struct ScanSh {
    union {
        unsigned long long smat[MCAP * NWP];       // fast path: 32 KB staged matrix
        struct {
            float x1[SLOTS], y1[SLOTS], x2[SLOTS], y2[SLOTS];
            unsigned char kp[SLOTS];
        } fb;                                       // fallback arrays (~13 KB)
    } u;
};

__global__ __launch_bounds__(256)
void scan_kernel(const int* __restrict__ wsCnt, const unsigned long long* __restrict__ supMat,
                 const float4* __restrict__ wsSBox,
                 int* __restrict__ wsKept, int* __restrict__ wsDst) {
    __shared__ ScanSh sh;
    const int b = blockIdx.x, tid = threadIdx.x;
    int M = wsCnt[b]; if (M > SLOTS) M = SLOTS;

    if (M <= MCAP) {
        // ---- parallel stage: global supMat slice -> LDS (coalesced, all 256 thr) ----
        const unsigned long long* rows = supMat + ((size_t)b * MCAP) * NWP;
        const int total = M * NWP;
        for (int t = tid; t < total; t += 256) sh.u.smat[t] = rows[t];
        __syncthreads();
        if (tid >= 64) return;                      // single wave; no barriers below
        const int lane = tid;
        unsigned long long keepW = 0ULL;
        int rem = M - (lane << 6);
        if (rem >= 64) keepW = ~0ULL; else if (rem > 0) keepW = (~0ULL) >> (64 - rem);
        const bool ld = (lane < NWP);
        unsigned long long A[8], B[8];
        int cnt = 0; bool done = false;
#define LOADB(buf, bs) { _Pragma("unroll") for (int k = 0; k < 8; ++k) { \
        int ii = (bs) + k; buf[k] = (ld && ii < M) ? sh.u.smat[ii * NWP + lane] : 0ULL; } }
#define PROCB(buf, bs) { _Pragma("unroll") for (int k = 0; k < 8; ++k) { \
        int ii = (bs) + k; \
        if (!done && ii < M) { \
            unsigned long long w64 = bcast64(keepW, ii >> 6); \
            if ((w64 >> (ii & 63)) & 1ULL) { \
                keepW &= ~buf[k]; \
                if (lane == 0) wsDst[b * MAXDET + cnt] = ii;  /* store RANK: no load */ \
                ++cnt; \
                if (cnt == MAXDET) done = true;   /* later bits can't reach rank<300 */ \
            } } } }
        LOADB(A, 0)
        for (int base = 0; base < M && !done; base += 16) {
            LOADB(B, base + 8)
            PROCB(A, base)
            LOADB(A, base + 16)
            PROCB(B, base + 8)
        }
#undef LOADB
#undef PROCB
        if (lane == 0) wsKept[b] = cnt;
    } else {
        // ---- fallback (M > MCAP, ~0 probability): barrier-serial greedy ----
        for (int r = tid; r < M; r += 256) {
            float4 v = wsSBox[b * SLOTS + r];
            sh.u.fb.x1[r] = v.x; sh.u.fb.y1[r] = v.y;
            sh.u.fb.x2[r] = v.z; sh.u.fb.y2[r] = v.w; sh.u.fb.kp[r] = 1;
        }
        __syncthreads();
        for (int i = 0; i < M; ++i) {
            if (sh.u.fb.kp[i]) {
                float ax1 = sh.u.fb.x1[i], ay1 = sh.u.fb.y1[i];
                float ax2 = sh.u.fb.x2[i], ay2 = sh.u.fb.y2[i];
                float aa = (ax2 - ax1) * (ay2 - ay1);
                for (int r = i + 1 + tid; r < M; r += 256) {
                    float bx1 = sh.u.fb.x1[r], by1 = sh.u.fb.y1[r];
                    float bx2 = sh.u.fb.x2[r], by2 = sh.u.fb.y2[r];
                    float ab = (bx2 - bx1) * (by2 - by1);
                    float ltx = fmaxf(ax1, bx1), lty = fmaxf(ay1, by1);
                    float rbx = fminf(ax2, bx2), rby = fminf(ay2, by2);
                    float ww = fmaxf(rbx - ltx, 0.0f), hh = fmaxf(rby - lty, 0.0f);
                    float inter = ww * hh;
                    float denom = ((aa + ab) - inter) + 1e-9f;
                    if ((inter / denom) > IOU_T) sh.u.fb.kp[r] = 0;
                }
            }
            __syncthreads();
        }
        if (tid == 0) {
            int c2 = 0;
            for (int r = 0; r < M && c2 < MAXDET; ++r)
                if (sh.u.fb.kp[r]) wsDst[b * MAXDET + c2++] = r;    // store RANK
            wsKept[b] = c2;
        }
    }
}

// ================= kernel 5: output write =================
__global__ __launch_bounds__(256)
void out_kernel(const float* __restrict__ score, const int* __restrict__ wsKept,
                const unsigned long long* __restrict__ wsKey,   // rank-sorted
                const int* __restrict__ wsDst, float* __restrict__ out) {
    const int b = blockIdx.x;
    const int e = blockIdx.y * 256 + threadIdx.x;
    if (e >= MAXDET * OUTC) return;
    const int row = e / OUTC, c = e - row * OUTC;
    float v = 0.0f;
    if (row < wsKept[b]) {
        unsigned long long key = wsKey[b * SLOTS + wsDst[b * MAXDET + row]];
        int n = (int)((key >> 16) & 0xFFFFULL);
        int cls = (int)((key >> 8) & 0xFFULL);
        int hw = n / 5, t5 = n - hw * 5;
        const float* base = score + (size_t)b * 425 * HWSZ + (size_t)(t5 * 85) * HWSZ + hw;
        if (c < 4) {
            float x = base[0];
            float y = base[HWSZ];
            float w = base[2 * HWSZ];
            float h = base[3 * HWSZ];
            float wh2 = w * 0.5f, hh2 = h * 0.5f;
            v = (c == 0) ? (x - wh2) : (c == 1) ? (y - hh2)
              : (c == 2) ? (x + wh2) : (y + hh2);
        } else if (c == 4) {
            v = __uint_as_float((~(unsigned int)(key >> 32)) & 0x7FFFFFFFu);
        } else if (c == 5) {
            v = (float)cls;
        } else {
            v = base[(c - 1) * HWSZ];              // raw logits
        }
    }
    out[(size_t)b * MAXDET * OUTC + e] = v;
}

// ================= mid-tier fallback: fused sort+NMS (proven structure) =================
struct SM2 {
    union {
        unsigned long long keys[SLOTS];
        unsigned long long supMat[MCAP * NWP];
    } u;
    float sbx1[SLOTS], sby1[SLOTS], sbx2[SLOTS], sby2[SLOTS];
    unsigned short sortedSlot[SLOTS];
    unsigned char keepFB[SLOTS];
};

__global__ __launch_bounds__(1024)
void nms_mid_kernel(const int* __restrict__ wsCnt, unsigned long long* __restrict__ wsKey,
                    const float4* __restrict__ wsBox, int* __restrict__ wsKept,
                    int* __restrict__ wsDst) {
    __shared__ SM2 s;
    const int b = blockIdx.x;
    const int tid = threadIdx.x;
    int M = wsCnt[b]; if (M > SLOTS) M = SLOTS;

    for (int i = tid; i < M; i += 1024) s.u.keys[i] = wsKey[b * SLOTS + i];
    __syncthreads();
    for (int vi = tid; vi < M; vi += 1024) {
        unsigned long long ki = s.u.keys[vi];
        int rank = 0;
        #pragma unroll 4
        for (int j = 0; j < M; ++j) rank += (s.u.keys[j] < ki) ? 1 : 0;
        s.sortedSlot[rank] = (unsigned short)vi;
    }
    __syncthreads();
    for (int r = tid; r < M; r += 1024) {
        int slot = s.sortedSlot[r];
        float4 bx = wsBox[b * SLOTS + slot];
        s.sbx1[r] = bx.x; s.sby1[r] = bx.y; s.sbx2[r] = bx.z; s.sby2[r] = bx.w;
        wsKey[b * SLOTS + r] = s.u.keys[slot];     // rank-sorted writeback for out_kernel
    }
    __syncthreads();

    if (M <= MCAP) {
        const int NW = (M + 63) >> 6;
        const int wid = tid >> 6, lane = tid & 63;
        for (int t = wid; t < M * NW; t += 16) {
            int i = t / NW, w = t - i * NW;
            float ax1 = s.sbx1[i], ay1 = s.sby1[i], ax2 = s.sbx2[i], ay2 = s.sby2[i];
            float aa = (ax2 - ax1) * (ay2 - ay1);
            int j = (w << 6) + lane;
            bool sup = false;
            if (j < M && j > i) {
                float bx1 = s.sbx1[j], by1 = s.sby1[j], bx2 = s.sbx2[j], by2 = s.sby2[j];
                float ab = (bx2 - bx1) * (by2 - by1);
                float ltx = fmaxf(ax1, bx1), lty = fmaxf(ay1, by1);
                float rbx = fminf(ax2, bx2), rby = fminf(ay2, by2);
                float ww = fmaxf(rbx - ltx, 0.0f), hh = fmaxf(rby - lty, 0.0f);
                float inter = ww * hh;
                float denom = ((aa + ab) - inter) + 1e-9f;
                sup = (inter / denom) > IOU_T;
            }
            unsigned long long mask = __ballot(sup);
            if (lane == 0) s.u.supMat[t] = mask;
        }
        __syncthreads();
        if (tid < 64) {
            const int lane = tid;
            unsigned long long keepW = 0;
            int rem = M - (lane << 6);
            if (rem >= 64) keepW = ~0ULL; else if (rem > 0) keepW = (~0ULL) >> (64 - rem);
            unsigned long long supA = (lane < NW && M > 0) ? s.u.supMat[lane] : 0ULL;
            unsigned long long supB = (lane < NW && M > 1) ? s.u.supMat[NW + lane] : 0ULL;
            int cnt = 0;
            for (int i = 0; i < M; ++i) {
                unsigned long long supN =
                    (lane < NW && (i + 2) < M) ? s.u.supMat[(i + 2) * NW + lane] : 0ULL;
                unsigned long long wv = __shfl(keepW, i >> 6, 64);
                if ((wv >> (i & 63)) & 1ULL) {
                    keepW &= ~supA;
                    if (lane == 0 && cnt < MAXDET) wsDst[b * MAXDET + cnt] = i;  // RANK
                    cnt++;
                }
                supA = supB; supB = supN;
            }
            if (lane == 0) wsKept[b] = (cnt < MAXDET) ? cnt : MAXDET;
        }
    } else {
        for (int r = tid; r < M; r += 1024) s.keepFB[r] = 1;
        __syncthreads();
        for (int i = 0; i < M; ++i) {
            if (s.keepFB[i]) {
                float ax1 = s.sbx1[i], ay1 = s.sby1[i], ax2 = s.sbx2[i], ay2 = s.sby2[i];
                float aa = (ax2 - ax1) * (ay2 - ay1);
                for (int r = i + 1 + tid; r < M; r += 1024) {
                    float bx1 = s.sbx1[r], by1 = s.sby1[r], bx2 = s.sbx2[r], by2 = s.sby2[r];
                    float ab = (bx2 - bx1) * (by2 - by1);
                    float ltx = fmaxf(ax1, bx1), lty = fmaxf(ay1, by1);
                    float rbx = fminf(ax2, bx2), rby = fminf(ay2, by2);
                    float ww = fmaxf(rbx - ltx, 0.0f), hh = fmaxf(rby - lty, 0.0f);
                    float inter = ww * hh;
                    float denom = ((aa + ab) - inter) + 1e-9f;
                    if ((inter / denom) > IOU_T) s.keepFB[r] = 0;
                }
            }
            __syncthreads();
        }
        if (tid == 0) {
            int cnt = 0;
            for (int r = 0; r < M && cnt < MAXDET; ++r)
                if (s.keepFB[r]) wsDst[b * MAXDET + cnt++] = r;  // RANK
            wsKept[b] = cnt;
        }
    }
}

// ================= last-resort fallback: round-2 single kernel (proven) =================
struct SMemFB {
    float bx1[NPRED], by1[NPRED], bx2[NPRED], by2[NPRED], area[NPRED];
    unsigned short sortedN[NPRED];
    union {
        unsigned long long vkey[NPRED];
        struct { float confR[MAXDET]; unsigned char jclsR[MAXDET]; } oi;
        unsigned char keepFB[NPRED];
    } u;
    unsigned short dstN[MAXDET];
    int validCount;
    int keptCount;
};

__device__ __forceinline__ void conf_argmax(const float* __restrict__ base, float obj,
                                            float& conf, int& bj) {
    float best = -INFINITY; int bjj = 0;
    #pragma unroll 8
    for (int k = 0; k < NCLS; ++k) {
        float v = base[(5 + k) * HWSZ] * obj;
        if (v > best) { best = v; bjj = k; }
    }
    conf = best; bj = bjj;
}

__global__ __launch_bounds__(1024)
void yolo_nms_single(const float* __restrict__ score, float* __restrict__ out) {
    __shared__ SMemFB s;
    const int b = blockIdx.x;
    const int tid = threadIdx.x;
    const float* sb = score + (size_t)b * 425 * HWSZ;
    if (tid == 0) s.validCount = 0;
    __syncthreads();
    for (int ci = tid; ci < NPRED; ci += 1024) {
        int t5 = ci / HWSZ;
        int hw = ci - t5 * HWSZ;
        int n = hw * 5 + t5;
        const float* base = sb + (size_t)(t5 * 85) * HWSZ + hw;
        float x = base[0], y = base[HWSZ], w = base[2 * HWSZ], h = base[3 * HWSZ];
        float obj = base[4 * HWSZ];
        float conf; int bj;
        conf_argmax(base, obj, conf, bj);
        bool valid = (obj > CONF_T) && (conf > CONF_T);
        float wh2 = w * 0.5f, hh2 = h * 0.5f;
        float x1 = x - wh2, y1 = y - hh2, x2 = x + wh2, y2 = y + hh2;
        float off = (float)bj * MAX_WH;
        float ox1 = x1 + off, oy1 = y1 + off, ox2 = x2 + off, oy2 = y2 + off;
        s.bx1[n] = ox1; s.by1[n] = oy1; s.bx2[n] = ox2; s.by2[n] = oy2;
        s.area[n] = (ox2 - ox1) * (oy2 - oy1);
        if (valid) {
            int slot = atomicAdd(&s.validCount, 1);
            unsigned int uu = __float_as_uint(conf);
            unsigned int desc = ~(uu | 0x80000000u);
            s.u.vkey[slot] = ((unsigned long long)desc << 32) | (unsigned int)n;
        }
    }
    __syncthreads();
    const int M = s.validCount;
    for (int vi = tid; vi < M; vi += 1024) {
        unsigned long long ki = s.u.vkey[vi];
        int rank = 0;
        for (int j = 0; j < M; ++j) rank += (s.u.vkey[j] < ki) ? 1 : 0;
        s.sortedN[rank] = (unsigned short)(ki & 0xFFFFULL);
    }
    __syncthreads();
    for (int r = tid; r < M; r += 1024) s.u.keepFB[r] = 1;
    __syncthreads();
    for (int i = 0; i < M; ++i) {
        if (s.u.keepFB[i]) {
            int ni = s.sortedN[i];
            float ax1 = s.bx1[ni], ay1 = s.by1[ni], ax2 = s.bx2[ni], ay2 = s.by2[ni];
            float aa = s.area[ni];
            for (int r = i + 1 + tid; r < M; r += 1024) {
                int nj = s.sortedN[r];
                float ltx = fmaxf(ax1, s.bx1[nj]);
                float lty = fmaxf(ay1, s.by1[nj]);
                float rbx = fminf(ax2, s.bx2[nj]);
                float rby = fminf(ay2, s.by2[nj]);
                float ww = fmaxf(rbx - ltx, 0.0f);
                float hh = fmaxf(rby - lty, 0.0f);
                float inter = ww * hh;
                float denom = ((aa + s.area[nj]) - inter) + 1e-9f;
                if ((inter / denom) > IOU_T) s.u.keepFB[r] = 0;
            }
        }
        __syncthreads();
    }
    if (tid == 0) {
        int cnt = 0;
        for (int r = 0; r < M && cnt < MAXDET; ++r)
            if (s.u.keepFB[r]) s.dstN[cnt++] = s.sortedN[r];
        s.keptCount = cnt;
    }
    __syncthreads();
    const int cnt = s.keptCount;
    if (tid < cnt) {
        int n = s.dstN[tid];
        int hw = n / 5, t5 = n - hw * 5;
        const float* base = sb + (size_t)(t5 * 85) * HWSZ + hw;
        float obj = base[4 * HWSZ];
        float conf; int bj;
        conf_argmax(base, obj, conf, bj);
        s.u.oi.confR[tid] = conf;
        s.u.oi.jclsR[tid] = (unsigned char)bj;
    }
    __syncthreads();
    float* ob = out + (size_t)b * MAXDET * OUTC;
    for (int e = tid; e < MAXDET * OUTC; e += 1024) {
        int row = e / OUTC, c = e - row * OUTC;
        float v = 0.0f;
        if (row < cnt) {
            int n = s.dstN[row];
            int hw = n / 5, t5 = n - hw * 5;
            const float* base = sb + (size_t)(t5 * 85) * HWSZ + hw;
            if (c < 4) {
                float x = base[0], y = base[HWSZ], w = base[2 * HWSZ], h = base[3 * HWSZ];
                float wh2 = w * 0.5f, hh2 = h * 0.5f;
                v = (c == 0) ? (x - wh2) : (c == 1) ? (y - hh2)
                  : (c == 2) ? (x + wh2) : (y + hh2);
            } else if (c == 4) {
                v = s.u.oi.confR[row];
            } else if (c == 5) {
                v = (float)s.u.oi.jclsR[row];
            } else {
                v = base[(c - 1) * HWSZ];
            }
        }
        ob[e] = v;
    }
}

extern "C" void kernel_launch(void* const* d_in, const int* in_sizes, int n_in,
                              void* d_out, int out_size, void* d_ws, size_t ws_size,
                              hipStream_t stream) {
    const float* score = (const float*)d_in[0];
    float* out = (float*)d_out;
    char* ws = (char*)d_ws;
    int* wsCnt = (int*)ws;
    int* wsKept = (int*)(ws + OFF_KEPT);
    unsigned long long* wsKey = (unsigned long long*)(ws + OFF_KEY);
    float4* wsBox = (float4*)(ws + OFF_BOX);
    int* wsDst = (int*)(ws + OFF_DST);
    float4* wsSBox = (float4*)(ws + OFF_SBOX);
    unsigned long long* supMat = (unsigned long long*)(ws + OFF_SUP);

    if (ws_size >= (size_t)WS_FULL) {
        hipMemsetAsync(ws, 0, 256, stream);
        prep_kernel<<<dim3(NIMG, 12), 128, 0, stream>>>(score, wsCnt, wsKey, wsBox);
        sort_kernel<<<NIMG, 1024, 0, stream>>>(wsCnt, wsKey, wsBox, wsSBox);
        supmat_kernel<<<dim3(NIMG, NWP), 512, 0, stream>>>(wsCnt, wsSBox, supMat);
        scan_kernel<<<NIMG, 256, 0, stream>>>(wsCnt, supMat, wsSBox, wsKept, wsDst);
        out_kernel<<<dim3(NIMG, 101), 256, 0, stream>>>(score, wsKept, wsKey, wsDst, out);
    } else if (ws_size >= (size_t)WS_MID) {
        hipMemsetAsync(ws, 0, 256, stream);
        prep_kernel<<<dim3(NIMG, 12), 128, 0, stream>>>(score, wsCnt, wsKey, wsBox);
        nms_mid_kernel<<<NIMG, 1024, 0, stream>>>(wsCnt, wsKey, wsBox, wsKept, wsDst);
        out_kernel<<<dim3(NIMG, 101), 256, 0, stream>>>(score, wsKept, wsKey, wsDst, out);
    } else {
        yolo_nms_single<<<NIMG, 1024, 0, stream>>>(score, out);
    }
}